// Round 15
// baseline (643.131 us; speedup 1.0000x reference)
//
#include <hip/hip_runtime.h>
#include <hip/hip_bf16.h>
#include <cfloat>
#include <climits>

#define NN_TOTAL 32768   // 8 * 4096 rows
#define NPTS     4096

typedef __attribute__((ext_vector_type(8))) short short8;
typedef __attribute__((ext_vector_type(4))) float f32x4;

__device__ __forceinline__ void split_bf16(float v, unsigned short& h, unsigned short& l)
{
    __hip_bfloat16 hb = __float2bfloat16(v);
    float hf = __bfloat162float(hb);
    __hip_bfloat16 lb = __float2bfloat16(v - hf);
    h = __builtin_bit_cast(unsigned short, hb);
    l = __builtin_bit_cast(unsigned short, lb);
}

// fast ELU negative branch: __expf -> v_exp_f32 (abs err <= ~1e-6 vs 2.4e-3 budget)
__device__ __forceinline__ float elu_fast(float v)
{
    return (v > 0.f) ? v : (__expf(v) - 1.f);
}

// async global->LDS, 16B per lane. LDS dest must be uniform_base + lane*16.
__device__ __forceinline__ void gload16(const unsigned short* g, unsigned short* l)
{
    __builtin_amdgcn_global_load_lds(
        (const __attribute__((address_space(1))) unsigned int*)g,
        (__attribute__((address_space(3))) unsigned int*)l, 16, 0, 0);
}

// ======================= fused weight prep: 12 layers in one launch =======================
struct PrepArgs {
    const float* W[12];
    int K[12];
    int N[12];
    int ksh[12];     // log2(Kp)
    int off[12];     // output element offset
    int blk0[12];    // starting block of layer
};

__global__ __launch_bounds__(256) void prep_all(
    PrepArgs a, unsigned short* __restrict__ th, unsigned short* __restrict__ tl)
{
    int l = 0;
    #pragma unroll
    for (int j = 1; j < 12; ++j) l += (blockIdx.x >= (unsigned)a.blk0[j]) ? 1 : 0;
    const int le = (blockIdx.x - a.blk0[l]) * 256 + threadIdx.x;
    const int ksh = a.ksh[l];
    const int n = le >> ksh;
    const int k = le & ((1 << ksh) - 1);
    const float v = (n < a.N[l] && k < a.K[l]) ? a.W[l][(size_t)k * a.N[l] + n] : 0.f;
    unsigned short h, lo;
    split_bf16(v, h, lo);
    th[a.off[l] + le] = h;
    tl[a.off[l] + le] = lo;
}

// ======================= activation packers (fp32 -> zero-padded 64-wide bf16 hi/lo) ==========
__global__ __launch_bounds__(256) void pack_x64(   // x[M][12] -> [M][64]
    const float* __restrict__ x, unsigned short* __restrict__ Xh, unsigned short* __restrict__ Xl)
{
    const int gid = blockIdx.x * 256 + threadIdx.x;   // M*8 threads
    const int r = gid >> 3, c8 = (gid & 7) * 8;
    unsigned short h[8], l[8];
    #pragma unroll
    for (int j = 0; j < 8; ++j) {
        const int col = c8 + j;
        const float v = (col < 12) ? x[(size_t)r * 12 + col] : 0.f;
        split_bf16(v, h[j], l[j]);
    }
    *(int4*)(Xh + (size_t)r * 64 + c8) = *(int4*)h;
    *(int4*)(Xl + (size_t)r * 64 + c8) = *(int4*)l;
}

__global__ __launch_bounds__(256) void cat2_pack(  // [x(12) | emb(32)] -> [M][64]
    const float* __restrict__ x, const float* __restrict__ emb,
    unsigned short* __restrict__ Xh, unsigned short* __restrict__ Xl)
{
    const int gid = blockIdx.x * 256 + threadIdx.x;   // M*8 threads
    const int r = gid >> 3, c8 = (gid & 7) * 8;
    unsigned short h[8], l[8];
    #pragma unroll
    for (int j = 0; j < 8; ++j) {
        const int col = c8 + j;
        float v = 0.f;
        if (col < 12)      v = x[(size_t)r * 12 + col];
        else if (col < 44) v = emb[(size_t)r * 32 + (col - 12)];
        split_bf16(v, h[j], l[j]);
    }
    *(int4*)(Xh + (size_t)r * 64 + c8) = *(int4*)h;
    *(int4*)(Xl + (size_t)r * 64 + c8) = *(int4*)l;
}

__global__ __launch_bounds__(256) void cat3_pack(  // [x(12) | preds_id(6)] -> [M][64]
    const float* __restrict__ x, const float* __restrict__ dout,
    unsigned short* __restrict__ Xh, unsigned short* __restrict__ Xl)
{
    const int gid = blockIdx.x * 256 + threadIdx.x;   // M*8 threads
    const int r = gid >> 3, c8 = (gid & 7) * 8;
    unsigned short h[8], l[8];
    #pragma unroll
    for (int j = 0; j < 8; ++j) {
        const int col = c8 + j;
        float v = 0.f;
        if (col < 12)      v = x[(size_t)r * 12 + col];
        else if (col < 18) v = dout[(size_t)r * 12 + (col - 12)];
        split_bf16(v, h[j], l[j]);
    }
    *(int4*)(Xh + (size_t)r * 64 + c8) = *(int4*)h;
    *(int4*)(Xl + (size_t)r * 64 + c8) = *(int4*)l;
}

// ======================= MFMA bf16x3 GEMM: 2-phase pipelined, BK=32, double-buffered LDS ======
template<int MF, int NF>
__global__ __launch_bounds__(256, (MF == 2 ? 3 : 4)) void gemm_mfma3(
    const unsigned short* __restrict__ Ah, const unsigned short* __restrict__ Al,
    const unsigned short* __restrict__ Bh, const unsigned short* __restrict__ Bl,
    const float* __restrict__ bias, int Kp, int N, int act,
    float* __restrict__ Cf, int ldcf,
    unsigned short* __restrict__ Ch, unsigned short* __restrict__ Cl, int ldcb, int padN)
{
    constexpr int BM = MF * 32;
    constexpr int PA = BM * 32;          // shorts per A half (h or l) per phase
    constexpr int PB = NF * 32 * 32;     // shorts per B half per phase
    constexpr int PH = 2 * PA + 2 * PB;  // shorts per phase
    __shared__ unsigned short lds[2 * PH];

    const int tid  = threadIdx.x;
    const int wave = tid >> 6, lane = tid & 63;
    const int wr = wave >> 1, wc = wave & 1;
    const int row0 = blockIdx.x * BM;
    const int col0 = blockIdx.y * (NF * 32);
    const int r16 = lane & 15, kg = lane >> 4;

    f32x4 acc[MF][NF];
    #pragma unroll
    for (int m = 0; m < MF; ++m)
        #pragma unroll
        for (int n = 0; n < NF; ++n)
            #pragma unroll
            for (int r = 0; r < 4; ++r) acc[m][n][r] = 0.f;

    auto STAGE = [&](int p, int k0) {
        unsigned short* base = lds + p * PH;
        #pragma unroll
        for (int c = tid; c < BM * 4; c += 256) {
            const int r  = c >> 2;
            const int kc = ((c & 3) ^ (r & 3)) * 8;          // inverse-swizzled source chunk
            const size_t go = (size_t)(row0 + r) * Kp + k0 + kc;
            gload16(Ah + go, base + c * 8);
            gload16(Al + go, base + PA + c * 8);
        }
        #pragma unroll
        for (int c = tid; c < NF * 128; c += 256) {
            const int r  = c >> 2;
            const int kc = ((c & 3) ^ (r & 3)) * 8;
            const size_t go = (size_t)(col0 + r) * Kp + k0 + kc;
            gload16(Bh + go, base + 2 * PA + c * 8);
            gload16(Bl + go, base + 2 * PA + PB + c * 8);
        }
    };

    auto COMPUTE = [&](int p) {
        unsigned short* base = lds + p * PH;
        short8 ah[MF], al[MF], bh[NF], bl[NF];
        #pragma unroll
        for (int m = 0; m < MF; ++m) {
            const int rr = wr * (MF * 16) + m * 16 + r16;
            const int off = rr * 32 + ((kg ^ (rr & 3)) * 8);  // swizzled read
            ah[m] = *(const short8*)&base[off];
            al[m] = *(const short8*)&base[PA + off];
        }
        #pragma unroll
        for (int n = 0; n < NF; ++n) {
            const int br = (NF == 4 ? wc * 64 + n * 16 : wc * 16) + r16;
            const int off = br * 32 + ((kg ^ (br & 3)) * 8);
            bh[n] = *(const short8*)&base[2 * PA + off];
            bl[n] = *(const short8*)&base[2 * PA + PB + off];
        }
        #pragma unroll
        for (int m = 0; m < MF; ++m)
            #pragma unroll
            for (int n = 0; n < NF; ++n) {
                acc[m][n] = __builtin_amdgcn_mfma_f32_16x16x32_bf16(ah[m], bh[n], acc[m][n], 0, 0, 0);
                acc[m][n] = __builtin_amdgcn_mfma_f32_16x16x32_bf16(ah[m], bl[n], acc[m][n], 0, 0, 0);
                acc[m][n] = __builtin_amdgcn_mfma_f32_16x16x32_bf16(al[m], bh[n], acc[m][n], 0, 0, 0);
            }
    };

    const int nt = Kp >> 5;
    STAGE(0, 0);
    __syncthreads();                 // drain prologue loads
    int cur = 0;
    for (int t = 0; t < nt; ++t) {
        if (t + 1 < nt) STAGE(cur ^ 1, (t + 1) * 32);   // issue next tile BEFORE compute
        COMPUTE(cur);
        __syncthreads();             // vmcnt(0)+barrier: next tile landed, cur free to reuse
        cur ^= 1;
    }

    // epilogue: C/D layout col=lane&15, row=(lane>>4)*4+reg
    #pragma unroll
    for (int m = 0; m < MF; ++m) {
        #pragma unroll
        for (int n = 0; n < NF; ++n) {
            const int col = col0 + (NF == 4 ? wc * 64 + n * 16 : wc * 16) + r16;
            #pragma unroll
            for (int r = 0; r < 4; ++r) {
                const int row = row0 + wr * (MF * 16) + m * 16 + kg * 4 + r;
                if (col < N) {
                    float v = acc[m][n][r] + bias[col];
                    if (act) v = elu_fast(v);
                    if (Cf) {
                        Cf[(size_t)row * ldcf + col] = v;
                    } else {
                        unsigned short h, l;
                        split_bf16(v, h, l);
                        Ch[(size_t)row * ldcb + col] = h;
                        Cl[(size_t)row * ldcb + col] = l;
                    }
                } else if (Ch && col < padN) {
                    Ch[(size_t)row * ldcb + col] = 0;
                    Cl[(size_t)row * ldcb + col] = 0;
                }
            }
        }
    }
}

// ======================= GravNet: projections s,h and |s|^2 (conv 0 only) =======================
__global__ __launch_bounds__(64) void conv_proj(
    const float* __restrict__ emb, const float* __restrict__ Ws,
    const float* __restrict__ bs, const float* __restrict__ Wh,
    const float* __restrict__ bh,
    float* __restrict__ s_out, float* __restrict__ sq_out, float* __restrict__ h_out)
{
    __shared__ float ws_s[32 * 4];
    __shared__ float wh_s[32 * 8];
    __shared__ float bs_s[4];
    __shared__ float bh_s[8];
    const int tid = threadIdx.x;
    for (int i = tid; i < 128; i += 64) ws_s[i] = Ws[i];
    for (int i = tid; i < 256; i += 64) wh_s[i] = Wh[i];
    if (tid < 4) bs_s[tid] = bs[tid];
    if (tid >= 8 && tid < 16) bh_s[tid - 8] = bh[tid - 8];
    __syncthreads();

    const int row = blockIdx.x * 64 + tid;
    float e[32];
    #pragma unroll
    for (int i = 0; i < 8; i++)
        *(float4*)&e[i * 4] = *(const float4*)(emb + (size_t)row * 32 + i * 4);

    float sv[4];
    #pragma unroll
    for (int c = 0; c < 4; c++) {
        float a = e[0] * ws_s[c];
        #pragma unroll
        for (int k = 1; k < 32; k++) a = fmaf(e[k], ws_s[k * 4 + c], a);
        sv[c] = a + bs_s[c];
    }
    float sq = sv[0] * sv[0];
    sq = fmaf(sv[1], sv[1], sq);
    sq = fmaf(sv[2], sv[2], sq);
    sq = fmaf(sv[3], sv[3], sq);

    float hv[8];
    #pragma unroll
    for (int c = 0; c < 8; c++) {
        float a = e[0] * wh_s[c];
        #pragma unroll
        for (int k = 1; k < 32; k++) a = fmaf(e[k], wh_s[k * 8 + c], a);
        hv[c] = a + bh_s[c];
    }

    *(float4*)(s_out + (size_t)row * 4) = *(float4*)&sv[0];
    sq_out[row] = sq;
    *(float4*)(h_out + (size_t)row * 8)     = *(float4*)&hv[0];
    *(float4*)(h_out + (size_t)row * 8 + 4) = *(float4*)&hv[4];
}

// ======================= kNN top-4 v10: no-csq (recompute |s|^2 in-register) ====================
// r9 geometry (256 pts/block, 16 splits, 256-cand LDS tile) but the candidate's |s|^2 is
// recomputed from the staged float4 with the EXACT conv_proj fmaf chain (bit-identical d2;
// no selection can move). Trades the ds_read_b32 (5.8 LDS cyc -- LDS was the binding pipe
// at 8 waves/SIMD: ~145K cyc/CU vs VALU ~94K) for 4 VALU -> new balance ~VALU-bound.
__device__ __forceinline__ void merge44(const float* ad, const int* ai,
                                        const float* bd, const int* bi,
                                        float* od, int* oi)
{
    int a = 0, b = 0;
    #pragma unroll
    for (int k = 0; k < 4; ++k) {
        bool ta;
        if (a < 4 && b < 4)
            ta = (ad[a] < bd[b]) || (ad[a] == bd[b] && ai[a] < bi[b]);
        else
            ta = (a < 4);
        if (ta) { od[k] = ad[a]; oi[k] = ai[a]; ++a; }
        else    { od[k] = bd[b]; oi[k] = bi[b]; ++b; }
    }
}

__global__ __launch_bounds__(256) void knn_top4_part(
    const float* __restrict__ s,
    float* __restrict__ pd, int* __restrict__ pi)
{
    __shared__ float4 cs[256];

    const int tid  = threadIdx.x;
    const int pg   = blockIdx.x >> 4;          // point group (256 points)
    const int sp   = blockIdx.x & 15;          // candidate split (256 cands)
    const int p0   = pg << 8;
    const int base = (p0 >> 12) << 12;         // batch base row
    const int row  = p0 + tid;                 // this thread's point

    const float4 sn = *(const float4*)(s + (size_t)row * 4);
    float sqn = sn.x * sn.x;                   // bit-identical to conv_proj's sq chain
    sqn = fmaf(sn.y, sn.y, sqn);
    sqn = fmaf(sn.z, sn.z, sqn);
    sqn = fmaf(sn.w, sn.w, sqn);

    const int m0 = sp << 8;
    {
        const int gm = base + m0 + tid;
        cs[tid] = *(const float4*)(s + (size_t)gm * 4);
    }
    __syncthreads();

    float bd[4] = {FLT_MAX, FLT_MAX, FLT_MAX, FLT_MAX};
    int   bi[4] = {INT_MAX, INT_MAX, INT_MAX, INT_MAX};

    #pragma unroll 8
    for (int i = 0; i < 256; ++i) {
        const float4 cm = cs[i];
        float cq = cm.x * cm.x;                // bit-identical to conv_proj's sq chain
        cq = fmaf(cm.y, cm.y, cq);
        cq = fmaf(cm.z, cm.z, cq);
        cq = fmaf(cm.w, cm.w, cq);
        float dot = sn.x * cm.x;
        dot = fmaf(sn.y, cm.y, dot);
        dot = fmaf(sn.z, cm.z, dot);
        dot = fmaf(sn.w, cm.w, dot);
        const float d2 = (sqn + cq) - 2.f * dot;
        const int m = m0 + i;                  // ascending per thread
        const bool c3 = d2 < bd[3];
        const bool c2 = d2 < bd[2];
        const bool c1 = d2 < bd[1];
        const bool c0 = d2 < bd[0];
        bi[3] = c3 ? (c2 ? bi[2] : m) : bi[3];
        bi[2] = c2 ? (c1 ? bi[1] : m) : bi[2];
        bi[1] = c1 ? (c0 ? bi[0] : m) : bi[1];
        bi[0] = c0 ? m : bi[0];
        bd[3] = __builtin_amdgcn_fmed3f(bd[2], bd[3], d2);
        bd[2] = __builtin_amdgcn_fmed3f(bd[1], bd[2], d2);
        bd[1] = __builtin_amdgcn_fmed3f(bd[0], bd[1], d2);
        bd[0] = fminf(bd[0], d2);
    }

    // partial layout: [pg][sp][256 points][4]
    const size_t o = (((size_t)pg * 16 + sp) * 256 + tid) * 4;
    *(float4*)(pd + o) = *(float4*)&bd[0];
    *(int4*)(pi + o)   = *(int4*)&bi[0];
}

// ======================= GravNet: merge + aggregate + out-linear (+ fused next-conv proj) ======
__global__ __launch_bounds__(64) void conv_agg(
    const float* __restrict__ emb, const float* __restrict__ h,
    const float* __restrict__ pd, const int* __restrict__ pi,
    const float* __restrict__ Wo1, const float* __restrict__ Wo2,
    const float* __restrict__ bo2, float* __restrict__ out,
    const float* __restrict__ Ws2, const float* __restrict__ bs2,
    const float* __restrict__ Wh2, const float* __restrict__ bh2,
    float* __restrict__ s_out, float* __restrict__ sq_out, float* __restrict__ h_out)
{
    __shared__ float w1[1024];
    __shared__ float w2[512];
    __shared__ float b2[32];
    __shared__ float ws_s[128];
    __shared__ float wh_s[256];
    __shared__ float bs_s[4];
    __shared__ float bh_s[8];
    const int tid = threadIdx.x;
    for (int i = tid; i < 1024; i += 64) w1[i] = Wo1[i];
    for (int i = tid; i < 512;  i += 64) w2[i] = Wo2[i];
    if (tid < 32) b2[tid] = bo2[tid];
    if (Ws2) {
        for (int i = tid; i < 128; i += 64) ws_s[i] = Ws2[i];
        for (int i = tid; i < 256; i += 64) wh_s[i] = Wh2[i];
        if (tid < 4) bs_s[tid] = bs2[tid];
        if (tid >= 8 && tid < 16) bh_s[tid - 8] = bh2[tid - 8];
    }
    __syncthreads();

    const int row  = blockIdx.x * 64 + tid;
    const int pg   = row >> 8;
    const int ln   = row & 255;
    const int base = (row >> 12) << 12;

    // ---- fold-merge the 16 candidate-split partials (lexicographic (d2, idx))
    float ad[4];
    int   ai[4];
    {
        const size_t o = ((size_t)pg * 16 * 256 + ln) * 4;
        *(float4*)&ad[0] = *(const float4*)(pd + o);
        *(int4*)&ai[0]   = *(const int4*)(pi + o);
    }
    #pragma unroll
    for (int sp = 1; sp < 16; ++sp) {
        const size_t o = (((size_t)pg * 16 + sp) * 256 + ln) * 4;
        float bdv[4], od[4];
        int   biv[4], oi[4];
        *(float4*)&bdv[0] = *(const float4*)(pd + o);
        *(int4*)&biv[0]   = *(const int4*)(pi + o);
        merge44(ad, ai, bdv, biv, od, oi);
        #pragma unroll
        for (int k = 0; k < 4; ++k) { ad[k] = od[k]; ai[k] = oi[k]; }
    }

    // ---- gather + weighted mean/max aggregate
    float e[32];
    #pragma unroll
    for (int i = 0; i < 8; i++)
        *(float4*)&e[i * 4] = *(const float4*)(emb + (size_t)row * 32 + i * 4);

    float msum[8], mmax[8];
    #pragma unroll
    for (int dd = 0; dd < 8; dd++) { msum[dd] = 0.f; mmax[dd] = -FLT_MAX; }

    #pragma unroll
    for (int k = 0; k < 4; k++) {
        const int g    = base + ai[k];
        const float wk = __expf(-10.f * fmaxf(ad[k], 0.f));
        float hv[8];
        *(float4*)&hv[0] = *(const float4*)(h + (size_t)g * 8);
        *(float4*)&hv[4] = *(const float4*)(h + (size_t)g * 8 + 4);
        #pragma unroll
        for (int dd = 0; dd < 8; dd++) {
            const float m = hv[dd] * wk;
            msum[dd] += m;
            mmax[dd] = fmaxf(mmax[dd], m);
        }
    }

    float agg[16];
    #pragma unroll
    for (int dd = 0; dd < 8; dd++) { agg[dd] = msum[dd] * 0.25f; agg[8 + dd] = mmax[dd]; }

    float o32[32];
    #pragma unroll
    for (int j = 0; j < 32; j++) {
        float a = e[0] * w1[j];
        #pragma unroll
        for (int k = 1; k < 32; k++) a = fmaf(e[k], w1[k * 32 + j], a);
        float g = agg[0] * w2[j];
        #pragma unroll
        for (int k = 1; k < 16; k++) g = fmaf(agg[k], w2[k * 32 + j], g);
        o32[j] = a + g + b2[j];
        out[(size_t)row * 32 + j] = o32[j];
    }

    // ---- fused next-conv projection (bit-identical to conv_proj on same values)
    if (Ws2) {
        float sv[4];
        #pragma unroll
        for (int c = 0; c < 4; c++) {
            float a = o32[0] * ws_s[c];
            #pragma unroll
            for (int k = 1; k < 32; k++) a = fmaf(o32[k], ws_s[k * 4 + c], a);
            sv[c] = a + bs_s[c];
        }
        float sq2 = sv[0] * sv[0];
        sq2 = fmaf(sv[1], sv[1], sq2);
        sq2 = fmaf(sv[2], sv[2], sq2);
        sq2 = fmaf(sv[3], sv[3], sq2);

        float hv[8];
        #pragma unroll
        for (int c = 0; c < 8; c++) {
            float a = o32[0] * wh_s[c];
            #pragma unroll
            for (int k = 1; k < 32; k++) a = fmaf(o32[k], wh_s[k * 8 + c], a);
            hv[c] = a + bh_s[c];
        }
        *(float4*)(s_out + (size_t)row * 4) = *(float4*)&sv[0];
        sq_out[row] = sq2;
        *(float4*)(h_out + (size_t)row * 8)     = *(float4*)&hv[0];
        *(float4*)(h_out + (size_t)row * 8 + 4) = *(float4*)&hv[4];
    }
}

// ======================= host launcher =======================
extern "C" void kernel_launch(void* const* d_in, const int* in_sizes, int n_in,
                              void* d_out, int out_size, void* d_ws, size_t ws_size,
                              hipStream_t stream)
{
    const float* x = (const float*)d_in[0];
    const float* nn1_w[4] = {(const float*)d_in[1], (const float*)d_in[3], (const float*)d_in[5], (const float*)d_in[7]};
    const float* nn1_b[4] = {(const float*)d_in[2], (const float*)d_in[4], (const float*)d_in[6], (const float*)d_in[8]};
    const float* nn2_w[4] = {(const float*)d_in[9],  (const float*)d_in[11], (const float*)d_in[13], (const float*)d_in[15]};
    const float* nn2_b[4] = {(const float*)d_in[10], (const float*)d_in[12], (const float*)d_in[14], (const float*)d_in[16]};
    const float* nn3_w[4] = {(const float*)d_in[17], (const float*)d_in[19], (const float*)d_in[21], (const float*)d_in[23]};
    const float* nn3_b[4] = {(const float*)d_in[18], (const float*)d_in[20], (const float*)d_in[22], (const float*)d_in[24]};
    const float* conv_ws  = (const float*)d_in[25];  // [3,32,4]
    const float* conv_bs  = (const float*)d_in[26];  // [3,4]
    const float* conv_wh  = (const float*)d_in[27];  // [3,32,8]
    const float* conv_bh  = (const float*)d_in[28];  // [3,8]
    const float* conv_wo1 = (const float*)d_in[29];  // [3,32,32]
    const float* conv_wo2 = (const float*)d_in[30];  // [3,16,32]
    const float* conv_bo2 = (const float*)d_in[31];  // [3,32]

    float* outp = (float*)d_out;
    const int M = NN_TOTAL;

    // ---- workspace partition
    char* p = (char*)d_ws;
    auto take = [&](size_t bytes) { char* r = p; p += (bytes + 255) & ~size_t(255); return r; };
    unsigned short* Xa_h = (unsigned short*)take((size_t)M * 256 * 2);
    unsigned short* Xa_l = (unsigned short*)take((size_t)M * 256 * 2);
    unsigned short* Xb_h = (unsigned short*)take((size_t)M * 256 * 2);
    unsigned short* Xb_l = (unsigned short*)take((size_t)M * 256 * 2);
    float* embA = (float*)take((size_t)M * 32 * 4);
    float* embB = (float*)take((size_t)M * 32 * 4);
    unsigned short* WH = (unsigned short*)take((size_t)450000 * 2);
    unsigned short* WL = (unsigned short*)take((size_t)450000 * 2);

    // conv scratch aliased over Xa..Xb (all four dead during conv loop)
    char* q = (char*)Xa_h;
    auto takeq = [&](size_t bytes) { char* r = q; q += (bytes + 255) & ~size_t(255); return r; };
    float* sbuf  = (float*)takeq((size_t)M * 4 * 4);
    float* sqb   = (float*)takeq((size_t)M * 4);
    float* hbufA = (float*)takeq((size_t)M * 8 * 4);
    float* hbufB = (float*)takeq((size_t)M * 8 * 4);
    float* pdb   = (float*)takeq((size_t)M * 16 * 4 * 4);
    int*   pib   = (int*)takeq((size_t)M * 16 * 4 * 4);

    // ---- fused weight prep (Kp multiple of 64; Np=32 for narrow layers)
    struct LW { int K, N, Kp, Np, off; };
    LW lw[12];
    const float* Ws_[12] = {nn1_w[0], nn1_w[1], nn1_w[2], nn1_w[3],
                            nn2_w[0], nn2_w[1], nn2_w[2], nn2_w[3],
                            nn3_w[0], nn3_w[1], nn3_w[2], nn3_w[3]};
    const int Ks_[12] = {12, 126, 126, 126,  44, 256, 256, 256,  18, 256, 256, 256};
    const int Ns_[12] = {126, 126, 126, 32,  256, 256, 256, 6,   256, 256, 256, 6};
    PrepArgs pa;
    int off = 0, blk = 0;
    for (int i = 0; i < 12; ++i) {
        lw[i].K = Ks_[i]; lw[i].N = Ns_[i];
        lw[i].Kp = (Ks_[i] + 63) & ~63;
        lw[i].Np = (Ns_[i] <= 32) ? 32 : ((Ns_[i] + 127) & ~127);
        lw[i].off = off;
        pa.W[i] = Ws_[i];
        pa.K[i] = Ks_[i]; pa.N[i] = Ns_[i];
        pa.ksh[i] = __builtin_ctz(lw[i].Kp);
        pa.off[i] = off;
        pa.blk0[i] = blk;
        off += lw[i].Kp * lw[i].Np;
        blk += lw[i].Kp * lw[i].Np / 256;
    }
    prep_all<<<blk, 256, 0, stream>>>(pa, WH, WL);

    auto mfma = [&](const unsigned short* Ah, const unsigned short* Al, int li,
                    const float* bias, int act,
                    float* Cf, int ldcf,
                    unsigned short* Chh, unsigned short* Cll, int ldcb, int padN, int nf) {
        if (nf == 4) {
            dim3 g(M / 64, lw[li].Np / 128);
            gemm_mfma3<2, 4><<<g, 256, 0, stream>>>(Ah, Al, WH + lw[li].off, WL + lw[li].off,
                                                    bias, lw[li].Kp, lw[li].N, act,
                                                    Cf, ldcf, Chh, Cll, ldcb, padN);
        } else {
            dim3 g(M / 128, 1);
            gemm_mfma3<4, 1><<<g, 256, 0, stream>>>(Ah, Al, WH + lw[li].off, WL + lw[li].off,
                                                    bias, lw[li].Kp, lw[li].N, act,
                                                    Cf, ldcf, Chh, Cll, ldcb, padN);
        }
    };

    // ---- nn1: 12 -> 126 -> 126 -> 126 -> 32(emb, fp32)
    pack_x64<<<M * 8 / 256, 256, 0, stream>>>(x, Xa_h, Xa_l);
    mfma(Xa_h, Xa_l, 0, nn1_b[0], 1, nullptr, 0, Xb_h, Xb_l, 128, 128, 4);
    mfma(Xb_h, Xb_l, 1, nn1_b[1], 1, nullptr, 0, Xa_h, Xa_l, 128, 128, 4);
    mfma(Xa_h, Xa_l, 2, nn1_b[2], 1, nullptr, 0, Xb_h, Xb_l, 128, 128, 4);
    mfma(Xb_h, Xb_l, 3, nn1_b[3], 0, embA, 32, nullptr, nullptr, 0, 0, 1);

    // ---- 3 GravNet convs (proj of conv1,2 fused into agg of conv0,1; hbuf double-buffered)
    conv_proj<<<M / 64, 64, 0, stream>>>(
        embA, conv_ws, conv_bs, conv_wh, conv_bh, sbuf, sqb, hbufA);
    float* ecur = embA;  float* enext = embB;
    float* hcur = hbufA; float* hnext = hbufB;
    for (int i = 0; i < 3; i++) {
        knn_top4_part<<<(M / 256) * 16, 256, 0, stream>>>(sbuf, pdb, pib);
        const bool fuse = (i < 2);
        conv_agg<<<M / 64, 64, 0, stream>>>(
            ecur, hcur, pdb, pib,
            conv_wo1 + i * 1024, conv_wo2 + i * 512, conv_bo2 + i * 32, enext,
            fuse ? conv_ws + (i + 1) * 128 : nullptr,
            fuse ? conv_bs + (i + 1) * 4   : nullptr,
            fuse ? conv_wh + (i + 1) * 256 : nullptr,
            fuse ? conv_bh + (i + 1) * 8   : nullptr,
            sbuf, sqb, hnext);
        float* t = ecur; ecur = enext; enext = t;
        t = hcur; hcur = hnext; hnext = t;
    }
    // ecur == final emb

    // ---- nn2: cat(x,emb)=44 -> 256 -> 256 -> 256 -> 6 (d_out cols 0..5; last layer NF=1)
    cat2_pack<<<M * 8 / 256, 256, 0, stream>>>(x, ecur, Xa_h, Xa_l);
    mfma(Xa_h, Xa_l, 4, nn2_b[0], 1, nullptr, 0, Xb_h, Xb_l, 256, 256, 4);
    mfma(Xb_h, Xb_l, 5, nn2_b[1], 1, nullptr, 0, Xa_h, Xa_l, 256, 256, 4);
    mfma(Xa_h, Xa_l, 6, nn2_b[2], 1, nullptr, 0, Xb_h, Xb_l, 256, 256, 4);
    mfma(Xb_h, Xb_l, 7, nn2_b[3], 0, outp, 12, nullptr, nullptr, 0, 0, 1);

    // ---- nn3: cat(x,preds_id)=18 -> 256 -> 256 -> 256 -> 6 (d_out cols 6..11; last layer NF=1)
    cat3_pack<<<M * 8 / 256, 256, 0, stream>>>(x, outp, Xa_h, Xa_l);
    mfma(Xa_h, Xa_l, 8, nn3_b[0], 1, nullptr, 0, Xb_h, Xb_l, 256, 256, 4);
    mfma(Xb_h, Xb_l, 9, nn3_b[1], 1, nullptr, 0, Xa_h, Xa_l, 256, 256, 4);
    mfma(Xa_h, Xa_l, 10, nn3_b[2], 1, nullptr, 0, Xb_h, Xb_l, 256, 256, 4);
    mfma(Xb_h, Xb_l, 11, nn3_b[3], 0, outp + 6, 12, nullptr, nullptr, 0, 0, 1);
}

// Round 16
// 566.713 us; speedup vs baseline: 1.1348x; 1.1348x over previous
//
#include <hip/hip_runtime.h>
#include <hip/hip_bf16.h>
#include <cfloat>
#include <climits>

#define NN_TOTAL 32768   // 8 * 4096 rows
#define NPTS     4096

typedef __attribute__((ext_vector_type(8))) short short8;
typedef __attribute__((ext_vector_type(4))) float f32x4;

__device__ __forceinline__ void split_bf16(float v, unsigned short& h, unsigned short& l)
{
    __hip_bfloat16 hb = __float2bfloat16(v);
    float hf = __bfloat162float(hb);
    __hip_bfloat16 lb = __float2bfloat16(v - hf);
    h = __builtin_bit_cast(unsigned short, hb);
    l = __builtin_bit_cast(unsigned short, lb);
}

// fast ELU negative branch: __expf -> v_exp_f32 (abs err <= ~1e-6 vs 2.4e-3 budget)
__device__ __forceinline__ float elu_fast(float v)
{
    return (v > 0.f) ? v : (__expf(v) - 1.f);
}

// async global->LDS, 16B per lane. LDS dest must be uniform_base + lane*16.
__device__ __forceinline__ void gload16(const unsigned short* g, unsigned short* l)
{
    __builtin_amdgcn_global_load_lds(
        (const __attribute__((address_space(1))) unsigned int*)g,
        (__attribute__((address_space(3))) unsigned int*)l, 16, 0, 0);
}

// ======================= fused weight prep: 12 layers in one launch =======================
struct PrepArgs {
    const float* W[12];
    int K[12];
    int N[12];
    int ksh[12];     // log2(Kp)
    int off[12];     // output element offset
    int blk0[12];    // starting block of layer
};

__global__ __launch_bounds__(256) void prep_all(
    PrepArgs a, unsigned short* __restrict__ th, unsigned short* __restrict__ tl)
{
    int l = 0;
    #pragma unroll
    for (int j = 1; j < 12; ++j) l += (blockIdx.x >= (unsigned)a.blk0[j]) ? 1 : 0;
    const int le = (blockIdx.x - a.blk0[l]) * 256 + threadIdx.x;
    const int ksh = a.ksh[l];
    const int n = le >> ksh;
    const int k = le & ((1 << ksh) - 1);
    const float v = (n < a.N[l] && k < a.K[l]) ? a.W[l][(size_t)k * a.N[l] + n] : 0.f;
    unsigned short h, lo;
    split_bf16(v, h, lo);
    th[a.off[l] + le] = h;
    tl[a.off[l] + le] = lo;
}

// ======================= activation packers (fp32 -> zero-padded bf16 hi/lo) ==================
__global__ __launch_bounds__(256) void pack_x32(   // x[M][12] -> [M][32]
    const float* __restrict__ x, unsigned short* __restrict__ Xh, unsigned short* __restrict__ Xl)
{
    const int gid = blockIdx.x * 256 + threadIdx.x;   // M*4 threads
    const int r = gid >> 2, c8 = (gid & 3) * 8;
    unsigned short h[8], l[8];
    #pragma unroll
    for (int j = 0; j < 8; ++j) {
        const int col = c8 + j;
        const float v = (col < 12) ? x[(size_t)r * 12 + col] : 0.f;
        split_bf16(v, h[j], l[j]);
    }
    *(int4*)(Xh + (size_t)r * 32 + c8) = *(int4*)h;
    *(int4*)(Xl + (size_t)r * 32 + c8) = *(int4*)l;
}

__global__ __launch_bounds__(256) void cat2_pack(  // [x(12) | emb(32)] -> [M][64]
    const float* __restrict__ x, const float* __restrict__ emb,
    unsigned short* __restrict__ Xh, unsigned short* __restrict__ Xl)
{
    const int gid = blockIdx.x * 256 + threadIdx.x;   // M*8 threads
    const int r = gid >> 3, c8 = (gid & 7) * 8;
    unsigned short h[8], l[8];
    #pragma unroll
    for (int j = 0; j < 8; ++j) {
        const int col = c8 + j;
        float v = 0.f;
        if (col < 12)      v = x[(size_t)r * 12 + col];
        else if (col < 44) v = emb[(size_t)r * 32 + (col - 12)];
        split_bf16(v, h[j], l[j]);
    }
    *(int4*)(Xh + (size_t)r * 64 + c8) = *(int4*)h;
    *(int4*)(Xl + (size_t)r * 64 + c8) = *(int4*)l;
}

__global__ __launch_bounds__(256) void cat3_pack(  // [x(12) | preds_id(6)] -> [M][32]
    const float* __restrict__ x, const float* __restrict__ dout,
    unsigned short* __restrict__ Xh, unsigned short* __restrict__ Xl)
{
    const int gid = blockIdx.x * 256 + threadIdx.x;   // M*4 threads
    const int r = gid >> 2, c8 = (gid & 3) * 8;
    unsigned short h[8], l[8];
    #pragma unroll
    for (int j = 0; j < 8; ++j) {
        const int col = c8 + j;
        float v = 0.f;
        if (col < 12)      v = x[(size_t)r * 12 + col];
        else if (col < 18) v = dout[(size_t)r * 12 + (col - 12)];
        split_bf16(v, h[j], l[j]);
    }
    *(int4*)(Xh + (size_t)r * 32 + c8) = *(int4*)h;
    *(int4*)(Xl + (size_t)r * 32 + c8) = *(int4*)l;
}

// ======================= MFMA bf16x3 GEMM: 2-phase pipelined, BK=32, double-buffered LDS ======
template<int MF, int NF>
__global__ __launch_bounds__(256, (MF == 2 ? 3 : 4)) void gemm_mfma3(
    const unsigned short* __restrict__ Ah, const unsigned short* __restrict__ Al,
    const unsigned short* __restrict__ Bh, const unsigned short* __restrict__ Bl,
    const float* __restrict__ bias, int Kp, int N, int act,
    float* __restrict__ Cf, int ldcf,
    unsigned short* __restrict__ Ch, unsigned short* __restrict__ Cl, int ldcb, int padN)
{
    constexpr int BM = MF * 32;
    constexpr int PA = BM * 32;          // shorts per A half (h or l) per phase
    constexpr int PB = NF * 32 * 32;     // shorts per B half per phase
    constexpr int PH = 2 * PA + 2 * PB;  // shorts per phase
    __shared__ unsigned short lds[2 * PH];

    const int tid  = threadIdx.x;
    const int wave = tid >> 6, lane = tid & 63;
    const int wr = wave >> 1, wc = wave & 1;
    const int row0 = blockIdx.x * BM;
    const int col0 = blockIdx.y * (NF * 32);
    const int r16 = lane & 15, kg = lane >> 4;

    f32x4 acc[MF][NF];
    #pragma unroll
    for (int m = 0; m < MF; ++m)
        #pragma unroll
        for (int n = 0; n < NF; ++n)
            #pragma unroll
            for (int r = 0; r < 4; ++r) acc[m][n][r] = 0.f;

    auto STAGE = [&](int p, int k0) {
        unsigned short* base = lds + p * PH;
        #pragma unroll
        for (int c = tid; c < BM * 4; c += 256) {
            const int r  = c >> 2;
            const int kc = ((c & 3) ^ (r & 3)) * 8;          // inverse-swizzled source chunk
            const size_t go = (size_t)(row0 + r) * Kp + k0 + kc;
            gload16(Ah + go, base + c * 8);
            gload16(Al + go, base + PA + c * 8);
        }
        #pragma unroll
        for (int c = tid; c < NF * 128; c += 256) {
            const int r  = c >> 2;
            const int kc = ((c & 3) ^ (r & 3)) * 8;
            const size_t go = (size_t)(col0 + r) * Kp + k0 + kc;
            gload16(Bh + go, base + 2 * PA + c * 8);
            gload16(Bl + go, base + 2 * PA + PB + c * 8);
        }
    };

    auto COMPUTE = [&](int p) {
        unsigned short* base = lds + p * PH;
        short8 ah[MF], al[MF], bh[NF], bl[NF];
        #pragma unroll
        for (int m = 0; m < MF; ++m) {
            const int rr = wr * (MF * 16) + m * 16 + r16;
            const int off = rr * 32 + ((kg ^ (rr & 3)) * 8);  // swizzled read
            ah[m] = *(const short8*)&base[off];
            al[m] = *(const short8*)&base[PA + off];
        }
        #pragma unroll
        for (int n = 0; n < NF; ++n) {
            const int br = (NF == 4 ? wc * 64 + n * 16 : wc * 16) + r16;
            const int off = br * 32 + ((kg ^ (br & 3)) * 8);
            bh[n] = *(const short8*)&base[2 * PA + off];
            bl[n] = *(const short8*)&base[2 * PA + PB + off];
        }
        #pragma unroll
        for (int m = 0; m < MF; ++m)
            #pragma unroll
            for (int n = 0; n < NF; ++n) {
                acc[m][n] = __builtin_amdgcn_mfma_f32_16x16x32_bf16(ah[m], bh[n], acc[m][n], 0, 0, 0);
                acc[m][n] = __builtin_amdgcn_mfma_f32_16x16x32_bf16(ah[m], bl[n], acc[m][n], 0, 0, 0);
                acc[m][n] = __builtin_amdgcn_mfma_f32_16x16x32_bf16(al[m], bh[n], acc[m][n], 0, 0, 0);
            }
    };

    const int nt = Kp >> 5;
    STAGE(0, 0);
    __syncthreads();                 // drain prologue loads
    int cur = 0;
    for (int t = 0; t < nt; ++t) {
        if (t + 1 < nt) STAGE(cur ^ 1, (t + 1) * 32);   // issue next tile BEFORE compute
        COMPUTE(cur);
        __syncthreads();             // vmcnt(0)+barrier: next tile landed, cur free to reuse
        cur ^= 1;
    }

    // epilogue: C/D layout col=lane&15, row=(lane>>4)*4+reg
    #pragma unroll
    for (int m = 0; m < MF; ++m) {
        #pragma unroll
        for (int n = 0; n < NF; ++n) {
            const int col = col0 + (NF == 4 ? wc * 64 + n * 16 : wc * 16) + r16;
            #pragma unroll
            for (int r = 0; r < 4; ++r) {
                const int row = row0 + wr * (MF * 16) + m * 16 + kg * 4 + r;
                if (col < N) {
                    float v = acc[m][n][r] + bias[col];
                    if (act) v = elu_fast(v);
                    if (Cf) {
                        Cf[(size_t)row * ldcf + col] = v;
                    } else {
                        unsigned short h, l;
                        split_bf16(v, h, l);
                        Ch[(size_t)row * ldcb + col] = h;
                        Cl[(size_t)row * ldcb + col] = l;
                    }
                } else if (Ch && col < padN) {
                    Ch[(size_t)row * ldcb + col] = 0;
                    Cl[(size_t)row * ldcb + col] = 0;
                }
            }
        }
    }
}

// ======================= GravNet: projections s,h and |s|^2 (conv 0 only) =======================
__global__ __launch_bounds__(64) void conv_proj(
    const float* __restrict__ emb, const float* __restrict__ Ws,
    const float* __restrict__ bs, const float* __restrict__ Wh,
    const float* __restrict__ bh,
    float* __restrict__ s_out, float* __restrict__ sq_out, float* __restrict__ h_out)
{
    __shared__ float ws_s[32 * 4];
    __shared__ float wh_s[32 * 8];
    __shared__ float bs_s[4];
    __shared__ float bh_s[8];
    const int tid = threadIdx.x;
    for (int i = tid; i < 128; i += 64) ws_s[i] = Ws[i];
    for (int i = tid; i < 256; i += 64) wh_s[i] = Wh[i];
    if (tid < 4) bs_s[tid] = bs[tid];
    if (tid >= 8 && tid < 16) bh_s[tid - 8] = bh[tid - 8];
    __syncthreads();

    const int row = blockIdx.x * 64 + tid;
    float e[32];
    #pragma unroll
    for (int i = 0; i < 8; i++)
        *(float4*)&e[i * 4] = *(const float4*)(emb + (size_t)row * 32 + i * 4);

    float sv[4];
    #pragma unroll
    for (int c = 0; c < 4; c++) {
        float a = e[0] * ws_s[c];
        #pragma unroll
        for (int k = 1; k < 32; k++) a = fmaf(e[k], ws_s[k * 4 + c], a);
        sv[c] = a + bs_s[c];
    }
    float sq = sv[0] * sv[0];
    sq = fmaf(sv[1], sv[1], sq);
    sq = fmaf(sv[2], sv[2], sq);
    sq = fmaf(sv[3], sv[3], sq);

    float hv[8];
    #pragma unroll
    for (int c = 0; c < 8; c++) {
        float a = e[0] * wh_s[c];
        #pragma unroll
        for (int k = 1; k < 32; k++) a = fmaf(e[k], wh_s[k * 8 + c], a);
        hv[c] = a + bh_s[c];
    }

    *(float4*)(s_out + (size_t)row * 4) = *(float4*)&sv[0];
    sq_out[row] = sq;
    *(float4*)(h_out + (size_t)row * 8)     = *(float4*)&hv[0];
    *(float4*)(h_out + (size_t)row * 8 + 4) = *(float4*)&hv[4];
}

// ======================= kNN top-4 (r9 config: RP=1, 16 splits, 256 cands, csq staged) =========
__device__ __forceinline__ void merge44(const float* ad, const int* ai,
                                        const float* bd, const int* bi,
                                        float* od, int* oi)
{
    int a = 0, b = 0;
    #pragma unroll
    for (int k = 0; k < 4; ++k) {
        bool ta;
        if (a < 4 && b < 4)
            ta = (ad[a] < bd[b]) || (ad[a] == bd[b] && ai[a] < bi[b]);
        else
            ta = (a < 4);
        if (ta) { od[k] = ad[a]; oi[k] = ai[a]; ++a; }
        else    { od[k] = bd[b]; oi[k] = bi[b]; ++b; }
    }
}

__global__ __launch_bounds__(256) void knn_top4_part(
    const float* __restrict__ s, const float* __restrict__ sq,
    float* __restrict__ pd, int* __restrict__ pi)
{
    __shared__ float4 cs[256];
    __shared__ float  csq[256];

    const int tid  = threadIdx.x;
    const int pg   = blockIdx.x >> 4;          // point group (256 points)
    const int sp   = blockIdx.x & 15;          // candidate split (256 cands)
    const int p0   = pg << 8;
    const int base = (p0 >> 12) << 12;         // batch base row
    const int row  = p0 + tid;                 // this thread's point

    const float4 sn  = *(const float4*)(s + (size_t)row * 4);
    const float  sqn = sq[row];

    const int m0 = sp << 8;
    {
        const int gm = base + m0 + tid;
        cs[tid]  = *(const float4*)(s + (size_t)gm * 4);
        csq[tid] = sq[gm];
    }
    __syncthreads();

    float bd[4] = {FLT_MAX, FLT_MAX, FLT_MAX, FLT_MAX};
    int   bi[4] = {INT_MAX, INT_MAX, INT_MAX, INT_MAX};

    #pragma unroll 8
    for (int i = 0; i < 256; ++i) {
        const float4 cm = cs[i];
        const float  cq = csq[i];
        float dot = sn.x * cm.x;
        dot = fmaf(sn.y, cm.y, dot);
        dot = fmaf(sn.z, cm.z, dot);
        dot = fmaf(sn.w, cm.w, dot);
        const float d2 = (sqn + cq) - 2.f * dot;
        const int m = m0 + i;                  // ascending per thread
        const bool c3 = d2 < bd[3];
        const bool c2 = d2 < bd[2];
        const bool c1 = d2 < bd[1];
        const bool c0 = d2 < bd[0];
        bi[3] = c3 ? (c2 ? bi[2] : m) : bi[3];
        bi[2] = c2 ? (c1 ? bi[1] : m) : bi[2];
        bi[1] = c1 ? (c0 ? bi[0] : m) : bi[1];
        bi[0] = c0 ? m : bi[0];
        bd[3] = __builtin_amdgcn_fmed3f(bd[2], bd[3], d2);
        bd[2] = __builtin_amdgcn_fmed3f(bd[1], bd[2], d2);
        bd[1] = __builtin_amdgcn_fmed3f(bd[0], bd[1], d2);
        bd[0] = fminf(bd[0], d2);
    }

    // partial layout: [pg][sp][256 points][4]
    const size_t o = (((size_t)pg * 16 + sp) * 256 + tid) * 4;
    *(float4*)(pd + o) = *(float4*)&bd[0];
    *(int4*)(pi + o)   = *(int4*)&bi[0];
}

// ======================= GravNet: merge + aggregate + out-linear (+ fused next-conv proj) ======
__global__ __launch_bounds__(64) void conv_agg(
    const float* __restrict__ emb, const float* __restrict__ h,
    const float* __restrict__ pd, const int* __restrict__ pi,
    const float* __restrict__ Wo1, const float* __restrict__ Wo2,
    const float* __restrict__ bo2, float* __restrict__ out,
    const float* __restrict__ Ws2, const float* __restrict__ bs2,
    const float* __restrict__ Wh2, const float* __restrict__ bh2,
    float* __restrict__ s_out, float* __restrict__ sq_out, float* __restrict__ h_out)
{
    __shared__ float w1[1024];
    __shared__ float w2[512];
    __shared__ float b2[32];
    __shared__ float ws_s[128];
    __shared__ float wh_s[256];
    __shared__ float bs_s[4];
    __shared__ float bh_s[8];
    const int tid = threadIdx.x;
    for (int i = tid; i < 1024; i += 64) w1[i] = Wo1[i];
    for (int i = tid; i < 512;  i += 64) w2[i] = Wo2[i];
    if (tid < 32) b2[tid] = bo2[tid];
    if (Ws2) {
        for (int i = tid; i < 128; i += 64) ws_s[i] = Ws2[i];
        for (int i = tid; i < 256; i += 64) wh_s[i] = Wh2[i];
        if (tid < 4) bs_s[tid] = bs2[tid];
        if (tid >= 8 && tid < 16) bh_s[tid - 8] = bh2[tid - 8];
    }
    __syncthreads();

    const int row  = blockIdx.x * 64 + tid;
    const int pg   = row >> 8;
    const int ln   = row & 255;
    const int base = (row >> 12) << 12;

    // ---- fold-merge the 16 candidate-split partials (lexicographic (d2, idx))
    float ad[4];
    int   ai[4];
    {
        const size_t o = ((size_t)pg * 16 * 256 + ln) * 4;
        *(float4*)&ad[0] = *(const float4*)(pd + o);
        *(int4*)&ai[0]   = *(const int4*)(pi + o);
    }
    #pragma unroll
    for (int sp = 1; sp < 16; ++sp) {
        const size_t o = (((size_t)pg * 16 + sp) * 256 + ln) * 4;
        float bdv[4], od[4];
        int   biv[4], oi[4];
        *(float4*)&bdv[0] = *(const float4*)(pd + o);
        *(int4*)&biv[0]   = *(const int4*)(pi + o);
        merge44(ad, ai, bdv, biv, od, oi);
        #pragma unroll
        for (int k = 0; k < 4; ++k) { ad[k] = od[k]; ai[k] = oi[k]; }
    }

    // ---- gather + weighted mean/max aggregate
    float e[32];
    #pragma unroll
    for (int i = 0; i < 8; i++)
        *(float4*)&e[i * 4] = *(const float4*)(emb + (size_t)row * 32 + i * 4);

    float msum[8], mmax[8];
    #pragma unroll
    for (int dd = 0; dd < 8; dd++) { msum[dd] = 0.f; mmax[dd] = -FLT_MAX; }

    #pragma unroll
    for (int k = 0; k < 4; k++) {
        const int g    = base + ai[k];
        const float wk = __expf(-10.f * fmaxf(ad[k], 0.f));
        float hv[8];
        *(float4*)&hv[0] = *(const float4*)(h + (size_t)g * 8);
        *(float4*)&hv[4] = *(const float4*)(h + (size_t)g * 8 + 4);
        #pragma unroll
        for (int dd = 0; dd < 8; dd++) {
            const float m = hv[dd] * wk;
            msum[dd] += m;
            mmax[dd] = fmaxf(mmax[dd], m);
        }
    }

    float agg[16];
    #pragma unroll
    for (int dd = 0; dd < 8; dd++) { agg[dd] = msum[dd] * 0.25f; agg[8 + dd] = mmax[dd]; }

    float o32[32];
    #pragma unroll
    for (int j = 0; j < 32; j++) {
        float a = e[0] * w1[j];
        #pragma unroll
        for (int k = 1; k < 32; k++) a = fmaf(e[k], w1[k * 32 + j], a);
        float g = agg[0] * w2[j];
        #pragma unroll
        for (int k = 1; k < 16; k++) g = fmaf(agg[k], w2[k * 32 + j], g);
        o32[j] = a + g + b2[j];
        out[(size_t)row * 32 + j] = o32[j];
    }

    // ---- fused next-conv projection (bit-identical to conv_proj on same values)
    if (Ws2) {
        float sv[4];
        #pragma unroll
        for (int c = 0; c < 4; c++) {
            float a = o32[0] * ws_s[c];
            #pragma unroll
            for (int k = 1; k < 32; k++) a = fmaf(o32[k], ws_s[k * 4 + c], a);
            sv[c] = a + bs_s[c];
        }
        float sq2 = sv[0] * sv[0];
        sq2 = fmaf(sv[1], sv[1], sq2);
        sq2 = fmaf(sv[2], sv[2], sq2);
        sq2 = fmaf(sv[3], sv[3], sq2);

        float hv[8];
        #pragma unroll
        for (int c = 0; c < 8; c++) {
            float a = o32[0] * wh_s[c];
            #pragma unroll
            for (int k = 1; k < 32; k++) a = fmaf(o32[k], wh_s[k * 8 + c], a);
            hv[c] = a + bh_s[c];
        }
        *(float4*)(s_out + (size_t)row * 4) = *(float4*)&sv[0];
        sq_out[row] = sq2;
        *(float4*)(h_out + (size_t)row * 8)     = *(float4*)&hv[0];
        *(float4*)(h_out + (size_t)row * 8 + 4) = *(float4*)&hv[4];
    }
}

// ======================= host launcher =======================
extern "C" void kernel_launch(void* const* d_in, const int* in_sizes, int n_in,
                              void* d_out, int out_size, void* d_ws, size_t ws_size,
                              hipStream_t stream)
{
    const float* x = (const float*)d_in[0];
    const float* nn1_w[4] = {(const float*)d_in[1], (const float*)d_in[3], (const float*)d_in[5], (const float*)d_in[7]};
    const float* nn1_b[4] = {(const float*)d_in[2], (const float*)d_in[4], (const float*)d_in[6], (const float*)d_in[8]};
    const float* nn2_w[4] = {(const float*)d_in[9],  (const float*)d_in[11], (const float*)d_in[13], (const float*)d_in[15]};
    const float* nn2_b[4] = {(const float*)d_in[10], (const float*)d_in[12], (const float*)d_in[14], (const float*)d_in[16]};
    const float* nn3_w[4] = {(const float*)d_in[17], (const float*)d_in[19], (const float*)d_in[21], (const float*)d_in[23]};
    const float* nn3_b[4] = {(const float*)d_in[18], (const float*)d_in[20], (const float*)d_in[22], (const float*)d_in[24]};
    const float* conv_ws  = (const float*)d_in[25];  // [3,32,4]
    const float* conv_bs  = (const float*)d_in[26];  // [3,4]
    const float* conv_wh  = (const float*)d_in[27];  // [3,32,8]
    const float* conv_bh  = (const float*)d_in[28];  // [3,8]
    const float* conv_wo1 = (const float*)d_in[29];  // [3,32,32]
    const float* conv_wo2 = (const float*)d_in[30];  // [3,16,32]
    const float* conv_bo2 = (const float*)d_in[31];  // [3,32]

    float* outp = (float*)d_out;
    const int M = NN_TOTAL;

    // ---- workspace partition
    char* p = (char*)d_ws;
    auto take = [&](size_t bytes) { char* r = p; p += (bytes + 255) & ~size_t(255); return r; };
    unsigned short* Xa_h = (unsigned short*)take((size_t)M * 256 * 2);
    unsigned short* Xa_l = (unsigned short*)take((size_t)M * 256 * 2);
    unsigned short* Xb_h = (unsigned short*)take((size_t)M * 256 * 2);
    unsigned short* Xb_l = (unsigned short*)take((size_t)M * 256 * 2);
    float* embA = (float*)take((size_t)M * 32 * 4);
    float* embB = (float*)take((size_t)M * 32 * 4);
    unsigned short* WH = (unsigned short*)take((size_t)450000 * 2);
    unsigned short* WL = (unsigned short*)take((size_t)450000 * 2);

    // conv scratch aliased over Xa..Xb (all four dead during conv loop)
    char* q = (char*)Xa_h;
    auto takeq = [&](size_t bytes) { char* r = q; q += (bytes + 255) & ~size_t(255); return r; };
    float* sbuf  = (float*)takeq((size_t)M * 4 * 4);
    float* sqb   = (float*)takeq((size_t)M * 4);
    float* hbufA = (float*)takeq((size_t)M * 8 * 4);
    float* hbufB = (float*)takeq((size_t)M * 8 * 4);
    float* pdb   = (float*)takeq((size_t)M * 16 * 4 * 4);
    int*   pib   = (int*)takeq((size_t)M * 16 * 4 * 4);

    // ---- fused weight prep (Kp multiple of 32 for BK=32; Np=32 for narrow layers)
    struct LW { int K, N, Kp, Np, off; };
    LW lw[12];
    const float* Ws_[12] = {nn1_w[0], nn1_w[1], nn1_w[2], nn1_w[3],
                            nn2_w[0], nn2_w[1], nn2_w[2], nn2_w[3],
                            nn3_w[0], nn3_w[1], nn3_w[2], nn3_w[3]};
    const int Ks_[12] = {12, 126, 126, 126,  44, 256, 256, 256,  18, 256, 256, 256};
    const int Ns_[12] = {126, 126, 126, 32,  256, 256, 256, 6,   256, 256, 256, 6};
    PrepArgs pa;
    int off = 0, blk = 0;
    for (int i = 0; i < 12; ++i) {
        lw[i].K = Ks_[i]; lw[i].N = Ns_[i];
        lw[i].Kp = (Ks_[i] + 31) & ~31;
        lw[i].Np = (Ns_[i] <= 32) ? 32 : ((Ns_[i] + 127) & ~127);
        lw[i].off = off;
        pa.W[i] = Ws_[i];
        pa.K[i] = Ks_[i]; pa.N[i] = Ns_[i];
        pa.ksh[i] = __builtin_ctz(lw[i].Kp);
        pa.off[i] = off;
        pa.blk0[i] = blk;
        off += lw[i].Kp * lw[i].Np;
        blk += lw[i].Kp * lw[i].Np / 256;
    }
    prep_all<<<blk, 256, 0, stream>>>(pa, WH, WL);

    auto mfma = [&](const unsigned short* Ah, const unsigned short* Al, int li,
                    const float* bias, int act,
                    float* Cf, int ldcf,
                    unsigned short* Chh, unsigned short* Cll, int ldcb, int padN, int nf) {
        if (nf == 4) {
            dim3 g(M / 64, lw[li].Np / 128);
            gemm_mfma3<2, 4><<<g, 256, 0, stream>>>(Ah, Al, WH + lw[li].off, WL + lw[li].off,
                                                    bias, lw[li].Kp, lw[li].N, act,
                                                    Cf, ldcf, Chh, Cll, ldcb, padN);
        } else {
            dim3 g(M / 128, 1);
            gemm_mfma3<4, 1><<<g, 256, 0, stream>>>(Ah, Al, WH + lw[li].off, WL + lw[li].off,
                                                    bias, lw[li].Kp, lw[li].N, act,
                                                    Cf, ldcf, Chh, Cll, ldcb, padN);
        }
    };

    // ---- nn1: 12 -> 126 -> 126 -> 126 -> 32(emb, fp32). l0 Kp=32 (pack_x32 stride 32)
    pack_x32<<<M * 4 / 256, 256, 0, stream>>>(x, Xa_h, Xa_l);
    mfma(Xa_h, Xa_l, 0, nn1_b[0], 1, nullptr, 0, Xb_h, Xb_l, 128, 128, 4);
    mfma(Xb_h, Xb_l, 1, nn1_b[1], 1, nullptr, 0, Xa_h, Xa_l, 128, 128, 4);
    mfma(Xa_h, Xa_l, 2, nn1_b[2], 1, nullptr, 0, Xb_h, Xb_l, 128, 128, 4);
    mfma(Xb_h, Xb_l, 3, nn1_b[3], 0, embA, 32, nullptr, nullptr, 0, 0, 1);

    // ---- 3 GravNet convs (proj of conv1,2 fused into agg of conv0,1; hbuf double-buffered)
    conv_proj<<<M / 64, 64, 0, stream>>>(
        embA, conv_ws, conv_bs, conv_wh, conv_bh, sbuf, sqb, hbufA);
    float* ecur = embA;  float* enext = embB;
    float* hcur = hbufA; float* hnext = hbufB;
    for (int i = 0; i < 3; i++) {
        knn_top4_part<<<(M / 256) * 16, 256, 0, stream>>>(sbuf, sqb, pdb, pib);
        const bool fuse = (i < 2);
        conv_agg<<<M / 64, 64, 0, stream>>>(
            ecur, hcur, pdb, pib,
            conv_wo1 + i * 1024, conv_wo2 + i * 512, conv_bo2 + i * 32, enext,
            fuse ? conv_ws + (i + 1) * 128 : nullptr,
            fuse ? conv_bs + (i + 1) * 4   : nullptr,
            fuse ? conv_wh + (i + 1) * 256 : nullptr,
            fuse ? conv_bh + (i + 1) * 8   : nullptr,
            sbuf, sqb, hnext);
        float* t = ecur; ecur = enext; enext = t;
        t = hcur; hcur = hnext; hnext = t;
    }
    // ecur == final emb

    // ---- nn2: cat(x,emb)=44 -> 256 -> 256 -> 256 -> 6 (d_out cols 0..5; l4 Kp=64)
    cat2_pack<<<M * 8 / 256, 256, 0, stream>>>(x, ecur, Xa_h, Xa_l);
    mfma(Xa_h, Xa_l, 4, nn2_b[0], 1, nullptr, 0, Xb_h, Xb_l, 256, 256, 4);
    mfma(Xb_h, Xb_l, 5, nn2_b[1], 1, nullptr, 0, Xa_h, Xa_l, 256, 256, 4);
    mfma(Xa_h, Xa_l, 6, nn2_b[2], 1, nullptr, 0, Xb_h, Xb_l, 256, 256, 4);
    mfma(Xb_h, Xb_l, 7, nn2_b[3], 0, outp, 12, nullptr, nullptr, 0, 0, 1);

    // ---- nn3: cat(x,preds_id)=18 -> 256 -> 256 -> 256 -> 6 (l8 Kp=32; cat3 stride 32)
    cat3_pack<<<M * 4 / 256, 256, 0, stream>>>(x, outp, Xa_h, Xa_l);
    mfma(Xa_h, Xa_l, 8, nn3_b[0], 1, nullptr, 0, Xb_h, Xb_l, 256, 256, 4);
    mfma(Xb_h, Xb_l, 9, nn3_b[1], 1, nullptr, 0, Xa_h, Xa_l, 256, 256, 4);
    mfma(Xa_h, Xa_l, 10, nn3_b[2], 1, nullptr, 0, Xb_h, Xb_l, 256, 256, 4);
    mfma(Xb_h, Xb_l, 11, nn3_b[3], 0, outp + 6, 12, nullptr, nullptr, 0, 0, 1);
}

// Round 17
// 489.934 us; speedup vs baseline: 1.3127x; 1.1567x over previous
//
#include <hip/hip_runtime.h>
#include <hip/hip_bf16.h>
#include <cfloat>
#include <climits>

#define NN_TOTAL 32768   // 8 * 4096 rows
#define NPTS     4096

typedef __attribute__((ext_vector_type(8))) short short8;
typedef __attribute__((ext_vector_type(4))) float f32x4;

__device__ __forceinline__ void split_bf16(float v, unsigned short& h, unsigned short& l)
{
    __hip_bfloat16 hb = __float2bfloat16(v);
    float hf = __bfloat162float(hb);
    __hip_bfloat16 lb = __float2bfloat16(v - hf);
    h = __builtin_bit_cast(unsigned short, hb);
    l = __builtin_bit_cast(unsigned short, lb);
}

__device__ __forceinline__ unsigned short bf16_of(float v)
{
    __hip_bfloat16 b = __float2bfloat16(v);
    return __builtin_bit_cast(unsigned short, b);
}

// fast ELU negative branch: __expf -> v_exp_f32 (abs err <= ~1e-6 vs 8.7e-3 budget)
__device__ __forceinline__ float elu_fast(float v)
{
    return (v > 0.f) ? v : (__expf(v) - 1.f);
}

// async global->LDS, 16B per lane. LDS dest must be uniform_base + lane*16.
__device__ __forceinline__ void gload16(const unsigned short* g, unsigned short* l)
{
    __builtin_amdgcn_global_load_lds(
        (const __attribute__((address_space(1))) unsigned int*)g,
        (__attribute__((address_space(3))) unsigned int*)l, 16, 0, 0);
}

// ======================= fused weight prep: 12 layers in one launch =======================
struct PrepArgs {
    const float* W[12];
    int K[12];
    int N[12];
    int ksh[12];     // log2(Kp)
    int off[12];     // output element offset
    int blk0[12];    // starting block of layer
};

__global__ __launch_bounds__(256) void prep_all(
    PrepArgs a, unsigned short* __restrict__ th, unsigned short* __restrict__ tl)
{
    int l = 0;
    #pragma unroll
    for (int j = 1; j < 12; ++j) l += (blockIdx.x >= (unsigned)a.blk0[j]) ? 1 : 0;
    const int le = (blockIdx.x - a.blk0[l]) * 256 + threadIdx.x;
    const int ksh = a.ksh[l];
    const int n = le >> ksh;
    const int k = le & ((1 << ksh) - 1);
    const float v = (n < a.N[l] && k < a.K[l]) ? a.W[l][(size_t)k * a.N[l] + n] : 0.f;
    unsigned short h, lo;
    split_bf16(v, h, lo);
    th[a.off[l] + le] = h;
    tl[a.off[l] + le] = lo;
}

// ======================= activation packers ====================================================
__global__ __launch_bounds__(256) void pack_x32(   // x[M][12] -> [M][32] hi/lo (nn1: full prec)
    const float* __restrict__ x, unsigned short* __restrict__ Xh, unsigned short* __restrict__ Xl)
{
    const int gid = blockIdx.x * 256 + threadIdx.x;   // M*4 threads
    const int r = gid >> 2, c8 = (gid & 3) * 8;
    unsigned short h[8], l[8];
    #pragma unroll
    for (int j = 0; j < 8; ++j) {
        const int col = c8 + j;
        const float v = (col < 12) ? x[(size_t)r * 12 + col] : 0.f;
        split_bf16(v, h[j], l[j]);
    }
    *(int4*)(Xh + (size_t)r * 32 + c8) = *(int4*)h;
    *(int4*)(Xl + (size_t)r * 32 + c8) = *(int4*)l;
}

__global__ __launch_bounds__(256) void cat2_pack(  // [x(12) | emb(32)] -> [M][64] hi only
    const float* __restrict__ x, const float* __restrict__ emb,
    unsigned short* __restrict__ Xh)
{
    const int gid = blockIdx.x * 256 + threadIdx.x;   // M*8 threads
    const int r = gid >> 3, c8 = (gid & 7) * 8;
    unsigned short h[8];
    #pragma unroll
    for (int j = 0; j < 8; ++j) {
        const int col = c8 + j;
        float v = 0.f;
        if (col < 12)      v = x[(size_t)r * 12 + col];
        else if (col < 44) v = emb[(size_t)r * 32 + (col - 12)];
        h[j] = bf16_of(v);
    }
    *(int4*)(Xh + (size_t)r * 64 + c8) = *(int4*)h;
}

__global__ __launch_bounds__(256) void cat3_pack(  // [x(12) | preds_id(6)] -> [M][32] hi only
    const float* __restrict__ x, const float* __restrict__ dout,
    unsigned short* __restrict__ Xh)
{
    const int gid = blockIdx.x * 256 + threadIdx.x;   // M*4 threads
    const int r = gid >> 2, c8 = (gid & 3) * 8;
    unsigned short h[8];
    #pragma unroll
    for (int j = 0; j < 8; ++j) {
        const int col = c8 + j;
        float v = 0.f;
        if (col < 12)      v = x[(size_t)r * 12 + col];
        else if (col < 18) v = dout[(size_t)r * 12 + (col - 12)];
        h[j] = bf16_of(v);
    }
    *(int4*)(Xh + (size_t)r * 32 + c8) = *(int4*)h;
}

// ======================= MFMA GEMM: 2-phase pipelined, BK=32, double-buffered LDS ==============
// TWO=false (nn1/conv path): bf16x3, fp32-accurate (Ah*Bh + Ah*Bl + Al*Bh).
// TWO=true  (nn2/nn3): activations plain bf16, weights hi/lo (Ah*Bh + Ah*Bl, 2 MFMA);
//   A-lo never staged/read; bf16 output is single cvt. LDS/phase 24->20KB -> 4 blocks/CU.
template<int MF, int NF, bool TWO>
__global__ __launch_bounds__(256, (MF == 2 ? (TWO ? 4 : 3) : 4)) void gemm_mfma3(
    const unsigned short* __restrict__ Ah, const unsigned short* __restrict__ Al,
    const unsigned short* __restrict__ Bh, const unsigned short* __restrict__ Bl,
    const float* __restrict__ bias, int Kp, int N, int act,
    float* __restrict__ Cf, int ldcf,
    unsigned short* __restrict__ Ch, unsigned short* __restrict__ Cl, int ldcb, int padN)
{
    constexpr int BM  = MF * 32;
    constexpr int PA  = BM * 32;          // shorts per A half per phase
    constexpr int PB  = NF * 32 * 32;     // shorts per B half per phase
    constexpr int NAH = TWO ? 1 : 2;      // A halves staged
    constexpr int PH  = NAH * PA + 2 * PB;
    __shared__ unsigned short lds[2 * PH];

    const int tid  = threadIdx.x;
    const int wave = tid >> 6, lane = tid & 63;
    const int wr = wave >> 1, wc = wave & 1;
    const int row0 = blockIdx.x * BM;
    const int col0 = blockIdx.y * (NF * 32);
    const int r16 = lane & 15, kg = lane >> 4;

    f32x4 acc[MF][NF];
    #pragma unroll
    for (int m = 0; m < MF; ++m)
        #pragma unroll
        for (int n = 0; n < NF; ++n)
            #pragma unroll
            for (int r = 0; r < 4; ++r) acc[m][n][r] = 0.f;

    auto STAGE = [&](int p, int k0) {
        unsigned short* base = lds + p * PH;
        #pragma unroll
        for (int c = tid; c < BM * 4; c += 256) {
            const int r  = c >> 2;
            const int kc = ((c & 3) ^ (r & 3)) * 8;          // inverse-swizzled source chunk
            const size_t go = (size_t)(row0 + r) * Kp + k0 + kc;
            gload16(Ah + go, base + c * 8);
            if (!TWO) gload16(Al + go, base + PA + c * 8);
        }
        #pragma unroll
        for (int c = tid; c < NF * 128; c += 256) {
            const int r  = c >> 2;
            const int kc = ((c & 3) ^ (r & 3)) * 8;
            const size_t go = (size_t)(col0 + r) * Kp + k0 + kc;
            gload16(Bh + go, base + NAH * PA + c * 8);
            gload16(Bl + go, base + NAH * PA + PB + c * 8);
        }
    };

    auto COMPUTE = [&](int p) {
        unsigned short* base = lds + p * PH;
        short8 ah[MF], al[MF], bh[NF], bl[NF];
        #pragma unroll
        for (int m = 0; m < MF; ++m) {
            const int rr = wr * (MF * 16) + m * 16 + r16;
            const int off = rr * 32 + ((kg ^ (rr & 3)) * 8);  // swizzled read
            ah[m] = *(const short8*)&base[off];
            if (!TWO) al[m] = *(const short8*)&base[PA + off];
        }
        #pragma unroll
        for (int n = 0; n < NF; ++n) {
            const int br = (NF == 4 ? wc * 64 + n * 16 : wc * 16) + r16;
            const int off = br * 32 + ((kg ^ (br & 3)) * 8);
            bh[n] = *(const short8*)&base[NAH * PA + off];
            bl[n] = *(const short8*)&base[NAH * PA + PB + off];
        }
        #pragma unroll
        for (int m = 0; m < MF; ++m)
            #pragma unroll
            for (int n = 0; n < NF; ++n) {
                acc[m][n] = __builtin_amdgcn_mfma_f32_16x16x32_bf16(ah[m], bh[n], acc[m][n], 0, 0, 0);
                acc[m][n] = __builtin_amdgcn_mfma_f32_16x16x32_bf16(ah[m], bl[n], acc[m][n], 0, 0, 0);
                if (!TWO)
                    acc[m][n] = __builtin_amdgcn_mfma_f32_16x16x32_bf16(al[m], bh[n], acc[m][n], 0, 0, 0);
            }
    };

    const int nt = Kp >> 5;
    STAGE(0, 0);
    __syncthreads();                 // drain prologue loads
    int cur = 0;
    for (int t = 0; t < nt; ++t) {
        if (t + 1 < nt) STAGE(cur ^ 1, (t + 1) * 32);   // issue next tile BEFORE compute
        COMPUTE(cur);
        __syncthreads();             // vmcnt(0)+barrier: next tile landed, cur free to reuse
        cur ^= 1;
    }

    // epilogue: C/D layout col=lane&15, row=(lane>>4)*4+reg
    #pragma unroll
    for (int m = 0; m < MF; ++m) {
        #pragma unroll
        for (int n = 0; n < NF; ++n) {
            const int col = col0 + (NF == 4 ? wc * 64 + n * 16 : wc * 16) + r16;
            #pragma unroll
            for (int r = 0; r < 4; ++r) {
                const int row = row0 + wr * (MF * 16) + m * 16 + kg * 4 + r;
                if (col < N) {
                    float v = acc[m][n][r] + bias[col];
                    if (act) v = elu_fast(v);
                    if (Cf) {
                        Cf[(size_t)row * ldcf + col] = v;
                    } else if (TWO) {
                        Ch[(size_t)row * ldcb + col] = bf16_of(v);
                    } else {
                        unsigned short h, l;
                        split_bf16(v, h, l);
                        Ch[(size_t)row * ldcb + col] = h;
                        Cl[(size_t)row * ldcb + col] = l;
                    }
                } else if (Ch && col < padN) {
                    Ch[(size_t)row * ldcb + col] = 0;
                    if (!TWO) Cl[(size_t)row * ldcb + col] = 0;
                }
            }
        }
    }
}

// ======================= GravNet: projections s,h and |s|^2 (conv 0 only) =======================
__global__ __launch_bounds__(64) void conv_proj(
    const float* __restrict__ emb, const float* __restrict__ Ws,
    const float* __restrict__ bs, const float* __restrict__ Wh,
    const float* __restrict__ bh,
    float* __restrict__ s_out, float* __restrict__ sq_out, float* __restrict__ h_out)
{
    __shared__ float ws_s[32 * 4];
    __shared__ float wh_s[32 * 8];
    __shared__ float bs_s[4];
    __shared__ float bh_s[8];
    const int tid = threadIdx.x;
    for (int i = tid; i < 128; i += 64) ws_s[i] = Ws[i];
    for (int i = tid; i < 256; i += 64) wh_s[i] = Wh[i];
    if (tid < 4) bs_s[tid] = bs[tid];
    if (tid >= 8 && tid < 16) bh_s[tid - 8] = bh[tid - 8];
    __syncthreads();

    const int row = blockIdx.x * 64 + tid;
    float e[32];
    #pragma unroll
    for (int i = 0; i < 8; i++)
        *(float4*)&e[i * 4] = *(const float4*)(emb + (size_t)row * 32 + i * 4);

    float sv[4];
    #pragma unroll
    for (int c = 0; c < 4; c++) {
        float a = e[0] * ws_s[c];
        #pragma unroll
        for (int k = 1; k < 32; k++) a = fmaf(e[k], ws_s[k * 4 + c], a);
        sv[c] = a + bs_s[c];
    }
    float sq = sv[0] * sv[0];
    sq = fmaf(sv[1], sv[1], sq);
    sq = fmaf(sv[2], sv[2], sq);
    sq = fmaf(sv[3], sv[3], sq);

    float hv[8];
    #pragma unroll
    for (int c = 0; c < 8; c++) {
        float a = e[0] * wh_s[c];
        #pragma unroll
        for (int k = 1; k < 32; k++) a = fmaf(e[k], wh_s[k * 8 + c], a);
        hv[c] = a + bh_s[c];
    }

    *(float4*)(s_out + (size_t)row * 4) = *(float4*)&sv[0];
    sq_out[row] = sq;
    *(float4*)(h_out + (size_t)row * 8)     = *(float4*)&hv[0];
    *(float4*)(h_out + (size_t)row * 8 + 4) = *(float4*)&hv[4];
}

// ======================= kNN top-4 (r9 config: RP=1, 16 splits, 256 cands, csq staged) =========
__device__ __forceinline__ void merge44(const float* ad, const int* ai,
                                        const float* bd, const int* bi,
                                        float* od, int* oi)
{
    int a = 0, b = 0;
    #pragma unroll
    for (int k = 0; k < 4; ++k) {
        bool ta;
        if (a < 4 && b < 4)
            ta = (ad[a] < bd[b]) || (ad[a] == bd[b] && ai[a] < bi[b]);
        else
            ta = (a < 4);
        if (ta) { od[k] = ad[a]; oi[k] = ai[a]; ++a; }
        else    { od[k] = bd[b]; oi[k] = bi[b]; ++b; }
    }
}

__global__ __launch_bounds__(256) void knn_top4_part(
    const float* __restrict__ s, const float* __restrict__ sq,
    float* __restrict__ pd, int* __restrict__ pi)
{
    __shared__ float4 cs[256];
    __shared__ float  csq[256];

    const int tid  = threadIdx.x;
    const int pg   = blockIdx.x >> 4;          // point group (256 points)
    const int sp   = blockIdx.x & 15;          // candidate split (256 cands)
    const int p0   = pg << 8;
    const int base = (p0 >> 12) << 12;         // batch base row
    const int row  = p0 + tid;                 // this thread's point

    const float4 sn  = *(const float4*)(s + (size_t)row * 4);
    const float  sqn = sq[row];

    const int m0 = sp << 8;
    {
        const int gm = base + m0 + tid;
        cs[tid]  = *(const float4*)(s + (size_t)gm * 4);
        csq[tid] = sq[gm];
    }
    __syncthreads();

    float bd[4] = {FLT_MAX, FLT_MAX, FLT_MAX, FLT_MAX};
    int   bi[4] = {INT_MAX, INT_MAX, INT_MAX, INT_MAX};

    #pragma unroll 8
    for (int i = 0; i < 256; ++i) {
        const float4 cm = cs[i];
        const float  cq = csq[i];
        float dot = sn.x * cm.x;
        dot = fmaf(sn.y, cm.y, dot);
        dot = fmaf(sn.z, cm.z, dot);
        dot = fmaf(sn.w, cm.w, dot);
        const float d2 = (sqn + cq) - 2.f * dot;
        const int m = m0 + i;                  // ascending per thread
        const bool c3 = d2 < bd[3];
        const bool c2 = d2 < bd[2];
        const bool c1 = d2 < bd[1];
        const bool c0 = d2 < bd[0];
        bi[3] = c3 ? (c2 ? bi[2] : m) : bi[3];
        bi[2] = c2 ? (c1 ? bi[1] : m) : bi[2];
        bi[1] = c1 ? (c0 ? bi[0] : m) : bi[1];
        bi[0] = c0 ? m : bi[0];
        bd[3] = __builtin_amdgcn_fmed3f(bd[2], bd[3], d2);
        bd[2] = __builtin_amdgcn_fmed3f(bd[1], bd[2], d2);
        bd[1] = __builtin_amdgcn_fmed3f(bd[0], bd[1], d2);
        bd[0] = fminf(bd[0], d2);
    }

    // partial layout: [pg][sp][256 points][4]
    const size_t o = (((size_t)pg * 16 + sp) * 256 + tid) * 4;
    *(float4*)(pd + o) = *(float4*)&bd[0];
    *(int4*)(pi + o)   = *(int4*)&bi[0];
}

// ======================= GravNet: merge + aggregate + out-linear (+ fused next-conv proj) ======
__global__ __launch_bounds__(64) void conv_agg(
    const float* __restrict__ emb, const float* __restrict__ h,
    const float* __restrict__ pd, const int* __restrict__ pi,
    const float* __restrict__ Wo1, const float* __restrict__ Wo2,
    const float* __restrict__ bo2, float* __restrict__ out,
    const float* __restrict__ Ws2, const float* __restrict__ bs2,
    const float* __restrict__ Wh2, const float* __restrict__ bh2,
    float* __restrict__ s_out, float* __restrict__ sq_out, float* __restrict__ h_out)
{
    __shared__ float w1[1024];
    __shared__ float w2[512];
    __shared__ float b2[32];
    __shared__ float ws_s[128];
    __shared__ float wh_s[256];
    __shared__ float bs_s[4];
    __shared__ float bh_s[8];
    const int tid = threadIdx.x;
    for (int i = tid; i < 1024; i += 64) w1[i] = Wo1[i];
    for (int i = tid; i < 512;  i += 64) w2[i] = Wo2[i];
    if (tid < 32) b2[tid] = bo2[tid];
    if (Ws2) {
        for (int i = tid; i < 128; i += 64) ws_s[i] = Ws2[i];
        for (int i = tid; i < 256; i += 64) wh_s[i] = Wh2[i];
        if (tid < 4) bs_s[tid] = bs2[tid];
        if (tid >= 8 && tid < 16) bh_s[tid - 8] = bh2[tid - 8];
    }
    __syncthreads();

    const int row  = blockIdx.x * 64 + tid;
    const int pg   = row >> 8;
    const int ln   = row & 255;
    const int base = (row >> 12) << 12;

    // ---- fold-merge the 16 candidate-split partials (lexicographic (d2, idx))
    float ad[4];
    int   ai[4];
    {
        const size_t o = ((size_t)pg * 16 * 256 + ln) * 4;
        *(float4*)&ad[0] = *(const float4*)(pd + o);
        *(int4*)&ai[0]   = *(const int4*)(pi + o);
    }
    #pragma unroll
    for (int sp = 1; sp < 16; ++sp) {
        const size_t o = (((size_t)pg * 16 + sp) * 256 + ln) * 4;
        float bdv[4], od[4];
        int   biv[4], oi[4];
        *(float4*)&bdv[0] = *(const float4*)(pd + o);
        *(int4*)&biv[0]   = *(const int4*)(pi + o);
        merge44(ad, ai, bdv, biv, od, oi);
        #pragma unroll
        for (int k = 0; k < 4; ++k) { ad[k] = od[k]; ai[k] = oi[k]; }
    }

    // ---- gather + weighted mean/max aggregate
    float e[32];
    #pragma unroll
    for (int i = 0; i < 8; i++)
        *(float4*)&e[i * 4] = *(const float4*)(emb + (size_t)row * 32 + i * 4);

    float msum[8], mmax[8];
    #pragma unroll
    for (int dd = 0; dd < 8; dd++) { msum[dd] = 0.f; mmax[dd] = -FLT_MAX; }

    #pragma unroll
    for (int k = 0; k < 4; k++) {
        const int g    = base + ai[k];
        const float wk = __expf(-10.f * fmaxf(ad[k], 0.f));
        float hv[8];
        *(float4*)&hv[0] = *(const float4*)(h + (size_t)g * 8);
        *(float4*)&hv[4] = *(const float4*)(h + (size_t)g * 8 + 4);
        #pragma unroll
        for (int dd = 0; dd < 8; dd++) {
            const float m = hv[dd] * wk;
            msum[dd] += m;
            mmax[dd] = fmaxf(mmax[dd], m);
        }
    }

    float agg[16];
    #pragma unroll
    for (int dd = 0; dd < 8; dd++) { agg[dd] = msum[dd] * 0.25f; agg[8 + dd] = mmax[dd]; }

    float o32[32];
    #pragma unroll
    for (int j = 0; j < 32; j++) {
        float a = e[0] * w1[j];
        #pragma unroll
        for (int k = 1; k < 32; k++) a = fmaf(e[k], w1[k * 32 + j], a);
        float g = agg[0] * w2[j];
        #pragma unroll
        for (int k = 1; k < 16; k++) g = fmaf(agg[k], w2[k * 32 + j], g);
        o32[j] = a + g + b2[j];
        out[(size_t)row * 32 + j] = o32[j];
    }

    // ---- fused next-conv projection (bit-identical to conv_proj on same values)
    if (Ws2) {
        float sv[4];
        #pragma unroll
        for (int c = 0; c < 4; c++) {
            float a = o32[0] * ws_s[c];
            #pragma unroll
            for (int k = 1; k < 32; k++) a = fmaf(o32[k], ws_s[k * 4 + c], a);
            sv[c] = a + bs_s[c];
        }
        float sq2 = sv[0] * sv[0];
        sq2 = fmaf(sv[1], sv[1], sq2);
        sq2 = fmaf(sv[2], sv[2], sq2);
        sq2 = fmaf(sv[3], sv[3], sq2);

        float hv[8];
        #pragma unroll
        for (int c = 0; c < 8; c++) {
            float a = o32[0] * wh_s[c];
            #pragma unroll
            for (int k = 1; k < 32; k++) a = fmaf(o32[k], wh_s[k * 8 + c], a);
            hv[c] = a + bh_s[c];
        }
        *(float4*)(s_out + (size_t)row * 4) = *(float4*)&sv[0];
        sq_out[row] = sq2;
        *(float4*)(h_out + (size_t)row * 8)     = *(float4*)&hv[0];
        *(float4*)(h_out + (size_t)row * 8 + 4) = *(float4*)&hv[4];
    }
}

// ======================= host launcher =======================
extern "C" void kernel_launch(void* const* d_in, const int* in_sizes, int n_in,
                              void* d_out, int out_size, void* d_ws, size_t ws_size,
                              hipStream_t stream)
{
    const float* x = (const float*)d_in[0];
    const float* nn1_w[4] = {(const float*)d_in[1], (const float*)d_in[3], (const float*)d_in[5], (const float*)d_in[7]};
    const float* nn1_b[4] = {(const float*)d_in[2], (const float*)d_in[4], (const float*)d_in[6], (const float*)d_in[8]};
    const float* nn2_w[4] = {(const float*)d_in[9],  (const float*)d_in[11], (const float*)d_in[13], (const float*)d_in[15]};
    const float* nn2_b[4] = {(const float*)d_in[10], (const float*)d_in[12], (const float*)d_in[14], (const float*)d_in[16]};
    const float* nn3_w[4] = {(const float*)d_in[17], (const float*)d_in[19], (const float*)d_in[21], (const float*)d_in[23]};
    const float* nn3_b[4] = {(const float*)d_in[18], (const float*)d_in[20], (const float*)d_in[22], (const float*)d_in[24]};
    const float* conv_ws  = (const float*)d_in[25];  // [3,32,4]
    const float* conv_bs  = (const float*)d_in[26];  // [3,4]
    const float* conv_wh  = (const float*)d_in[27];  // [3,32,8]
    const float* conv_bh  = (const float*)d_in[28];  // [3,8]
    const float* conv_wo1 = (const float*)d_in[29];  // [3,32,32]
    const float* conv_wo2 = (const float*)d_in[30];  // [3,16,32]
    const float* conv_bo2 = (const float*)d_in[31];  // [3,32]

    float* outp = (float*)d_out;
    const int M = NN_TOTAL;

    // ---- workspace partition
    char* p = (char*)d_ws;
    auto take = [&](size_t bytes) { char* r = p; p += (bytes + 255) & ~size_t(255); return r; };
    unsigned short* Xa_h = (unsigned short*)take((size_t)M * 256 * 2);
    unsigned short* Xa_l = (unsigned short*)take((size_t)M * 256 * 2);
    unsigned short* Xb_h = (unsigned short*)take((size_t)M * 256 * 2);
    unsigned short* Xb_l = (unsigned short*)take((size_t)M * 256 * 2);
    float* embA = (float*)take((size_t)M * 32 * 4);
    float* embB = (float*)take((size_t)M * 32 * 4);
    unsigned short* WH = (unsigned short*)take((size_t)450000 * 2);
    unsigned short* WL = (unsigned short*)take((size_t)450000 * 2);

    // conv scratch aliased over Xa..Xb (all four dead during conv loop)
    char* q = (char*)Xa_h;
    auto takeq = [&](size_t bytes) { char* r = q; q += (bytes + 255) & ~size_t(255); return r; };
    float* sbuf  = (float*)takeq((size_t)M * 4 * 4);
    float* sqb   = (float*)takeq((size_t)M * 4);
    float* hbufA = (float*)takeq((size_t)M * 8 * 4);
    float* hbufB = (float*)takeq((size_t)M * 8 * 4);
    float* pdb   = (float*)takeq((size_t)M * 16 * 4 * 4);
    int*   pib   = (int*)takeq((size_t)M * 16 * 4 * 4);

    // ---- fused weight prep (Kp multiple of 32 for BK=32; Np=32 for narrow layers)
    struct LW { int K, N, Kp, Np, off; };
    LW lw[12];
    const float* Ws_[12] = {nn1_w[0], nn1_w[1], nn1_w[2], nn1_w[3],
                            nn2_w[0], nn2_w[1], nn2_w[2], nn2_w[3],
                            nn3_w[0], nn3_w[1], nn3_w[2], nn3_w[3]};
    const int Ks_[12] = {12, 126, 126, 126,  44, 256, 256, 256,  18, 256, 256, 256};
    const int Ns_[12] = {126, 126, 126, 32,  256, 256, 256, 6,   256, 256, 256, 6};
    PrepArgs pa;
    int off = 0, blk = 0;
    for (int i = 0; i < 12; ++i) {
        lw[i].K = Ks_[i]; lw[i].N = Ns_[i];
        lw[i].Kp = (Ks_[i] + 31) & ~31;
        lw[i].Np = (Ns_[i] <= 32) ? 32 : ((Ns_[i] + 127) & ~127);
        lw[i].off = off;
        pa.W[i] = Ws_[i];
        pa.K[i] = Ks_[i]; pa.N[i] = Ns_[i];
        pa.ksh[i] = __builtin_ctz(lw[i].Kp);
        pa.off[i] = off;
        pa.blk0[i] = blk;
        off += lw[i].Kp * lw[i].Np;
        blk += lw[i].Kp * lw[i].Np / 256;
    }
    prep_all<<<blk, 256, 0, stream>>>(pa, WH, WL);

    auto mfma = [&](const unsigned short* Ah, const unsigned short* Al, int li,
                    const float* bias, int act,
                    float* Cf, int ldcf,
                    unsigned short* Chh, unsigned short* Cll, int ldcb, int padN,
                    int nf, bool two) {
        if (nf == 4) {
            dim3 g(M / 64, lw[li].Np / 128);
            if (two)
                gemm_mfma3<2, 4, true><<<g, 256, 0, stream>>>(Ah, Al, WH + lw[li].off, WL + lw[li].off,
                    bias, lw[li].Kp, lw[li].N, act, Cf, ldcf, Chh, Cll, ldcb, padN);
            else
                gemm_mfma3<2, 4, false><<<g, 256, 0, stream>>>(Ah, Al, WH + lw[li].off, WL + lw[li].off,
                    bias, lw[li].Kp, lw[li].N, act, Cf, ldcf, Chh, Cll, ldcb, padN);
        } else {
            dim3 g(M / 128, 1);
            if (two)
                gemm_mfma3<4, 1, true><<<g, 256, 0, stream>>>(Ah, Al, WH + lw[li].off, WL + lw[li].off,
                    bias, lw[li].Kp, lw[li].N, act, Cf, ldcf, Chh, Cll, ldcb, padN);
            else
                gemm_mfma3<4, 1, false><<<g, 256, 0, stream>>>(Ah, Al, WH + lw[li].off, WL + lw[li].off,
                    bias, lw[li].Kp, lw[li].N, act, Cf, ldcf, Chh, Cll, ldcb, padN);
        }
    };

    // ---- nn1 (fp32-accurate bf16x3; feeds kNN selections): 12 -> 126^3 -> 32(emb fp32)
    pack_x32<<<M * 4 / 256, 256, 0, stream>>>(x, Xa_h, Xa_l);
    mfma(Xa_h, Xa_l, 0, nn1_b[0], 1, nullptr, 0, Xb_h, Xb_l, 128, 128, 4, false);
    mfma(Xb_h, Xb_l, 1, nn1_b[1], 1, nullptr, 0, Xa_h, Xa_l, 128, 128, 4, false);
    mfma(Xa_h, Xa_l, 2, nn1_b[2], 1, nullptr, 0, Xb_h, Xb_l, 128, 128, 4, false);
    mfma(Xb_h, Xb_l, 3, nn1_b[3], 0, embA, 32, nullptr, nullptr, 0, 0, 1, false);

    // ---- 3 GravNet convs (fp32; proj of conv1,2 fused into agg of conv0,1)
    conv_proj<<<M / 64, 64, 0, stream>>>(
        embA, conv_ws, conv_bs, conv_wh, conv_bh, sbuf, sqb, hbufA);
    float* ecur = embA;  float* enext = embB;
    float* hcur = hbufA; float* hnext = hbufB;
    for (int i = 0; i < 3; i++) {
        knn_top4_part<<<(M / 256) * 16, 256, 0, stream>>>(sbuf, sqb, pdb, pib);
        const bool fuse = (i < 2);
        conv_agg<<<M / 64, 64, 0, stream>>>(
            ecur, hcur, pdb, pib,
            conv_wo1 + i * 1024, conv_wo2 + i * 512, conv_bo2 + i * 32, enext,
            fuse ? conv_ws + (i + 1) * 128 : nullptr,
            fuse ? conv_bs + (i + 1) * 4   : nullptr,
            fuse ? conv_wh + (i + 1) * 256 : nullptr,
            fuse ? conv_bh + (i + 1) * 8   : nullptr,
            sbuf, sqb, hnext);
        float* t = ecur; ecur = enext; enext = t;
        t = hcur; hcur = hnext; hnext = t;
    }
    // ecur == final emb

    // ---- nn2 (TWO: bf16 activations, hi/lo weights; smooth path, no top-k downstream)
    cat2_pack<<<M * 8 / 256, 256, 0, stream>>>(x, ecur, Xa_h);
    mfma(Xa_h, nullptr, 4, nn2_b[0], 1, nullptr, 0, Xb_h, nullptr, 256, 256, 4, true);
    mfma(Xb_h, nullptr, 5, nn2_b[1], 1, nullptr, 0, Xa_h, nullptr, 256, 256, 4, true);
    mfma(Xa_h, nullptr, 6, nn2_b[2], 1, nullptr, 0, Xb_h, nullptr, 256, 256, 4, true);
    mfma(Xb_h, nullptr, 7, nn2_b[3], 0, outp, 12, nullptr, nullptr, 0, 0, 1, true);

    // ---- nn3 (TWO): cat(x,preds_id)=18 -> 256^3 -> 6 (d_out cols 6..11)
    cat3_pack<<<M * 4 / 256, 256, 0, stream>>>(x, outp, Xa_h);
    mfma(Xa_h, nullptr, 8, nn3_b[0], 1, nullptr, 0, Xb_h, nullptr, 256, 256, 4, true);
    mfma(Xb_h, nullptr, 9, nn3_b[1], 1, nullptr, 0, Xa_h, nullptr, 256, 256, 4, true);
    mfma(Xa_h, nullptr, 10, nn3_b[2], 1, nullptr, 0, Xb_h, nullptr, 256, 256, 4, true);
    mfma(Xb_h, nullptr, 11, nn3_b[3], 0, outp + 6, 12, nullptr, nullptr, 0, 0, 1, true);
}

// Round 18
// 477.810 us; speedup vs baseline: 1.3460x; 1.0254x over previous
//
#include <hip/hip_runtime.h>
#include <hip/hip_bf16.h>
#include <cfloat>
#include <climits>

#define NN_TOTAL 32768   // 8 * 4096 rows
#define NPTS     4096

typedef __attribute__((ext_vector_type(8))) short short8;
typedef __attribute__((ext_vector_type(4))) float f32x4;

__device__ __forceinline__ void split_bf16(float v, unsigned short& h, unsigned short& l)
{
    __hip_bfloat16 hb = __float2bfloat16(v);
    float hf = __bfloat162float(hb);
    __hip_bfloat16 lb = __float2bfloat16(v - hf);
    h = __builtin_bit_cast(unsigned short, hb);
    l = __builtin_bit_cast(unsigned short, lb);
}

__device__ __forceinline__ unsigned short bf16_of(float v)
{
    __hip_bfloat16 b = __float2bfloat16(v);
    return __builtin_bit_cast(unsigned short, b);
}

// fast ELU negative branch: __expf -> v_exp_f32 (abs err <= ~1e-6 vs 8.7e-3 budget)
__device__ __forceinline__ float elu_fast(float v)
{
    return (v > 0.f) ? v : (__expf(v) - 1.f);
}

// async global->LDS, 16B per lane. LDS dest must be uniform_base + lane*16.
__device__ __forceinline__ void gload16(const unsigned short* g, unsigned short* l)
{
    __builtin_amdgcn_global_load_lds(
        (const __attribute__((address_space(1))) unsigned int*)g,
        (__attribute__((address_space(3))) unsigned int*)l, 16, 0, 0);
}

// ======================= fused weight prep: 12 layers in one launch =======================
struct PrepArgs {
    const float* W[12];
    int K[12];
    int N[12];
    int ksh[12];     // log2(Kp)
    int off[12];     // output element offset
    int blk0[12];    // starting block of layer
};

__global__ __launch_bounds__(256) void prep_all(
    PrepArgs a, unsigned short* __restrict__ th, unsigned short* __restrict__ tl)
{
    int l = 0;
    #pragma unroll
    for (int j = 1; j < 12; ++j) l += (blockIdx.x >= (unsigned)a.blk0[j]) ? 1 : 0;
    const int le = (blockIdx.x - a.blk0[l]) * 256 + threadIdx.x;
    const int ksh = a.ksh[l];
    const int n = le >> ksh;
    const int k = le & ((1 << ksh) - 1);
    const float v = (n < a.N[l] && k < a.K[l]) ? a.W[l][(size_t)k * a.N[l] + n] : 0.f;
    unsigned short h, lo;
    split_bf16(v, h, lo);
    th[a.off[l] + le] = h;
    tl[a.off[l] + le] = lo;
}

// ======================= activation packers ====================================================
__global__ __launch_bounds__(256) void pack_x32(   // x[M][12] -> [M][32] hi/lo (nn1: full prec)
    const float* __restrict__ x, unsigned short* __restrict__ Xh, unsigned short* __restrict__ Xl)
{
    const int gid = blockIdx.x * 256 + threadIdx.x;   // M*4 threads
    const int r = gid >> 2, c8 = (gid & 3) * 8;
    unsigned short h[8], l[8];
    #pragma unroll
    for (int j = 0; j < 8; ++j) {
        const int col = c8 + j;
        const float v = (col < 12) ? x[(size_t)r * 12 + col] : 0.f;
        split_bf16(v, h[j], l[j]);
    }
    *(int4*)(Xh + (size_t)r * 32 + c8) = *(int4*)h;
    *(int4*)(Xl + (size_t)r * 32 + c8) = *(int4*)l;
}

__global__ __launch_bounds__(256) void cat2_pack(  // [x(12) | emb(32)] -> [M][64] hi only
    const float* __restrict__ x, const float* __restrict__ emb,
    unsigned short* __restrict__ Xh)
{
    const int gid = blockIdx.x * 256 + threadIdx.x;   // M*8 threads
    const int r = gid >> 3, c8 = (gid & 7) * 8;
    unsigned short h[8];
    #pragma unroll
    for (int j = 0; j < 8; ++j) {
        const int col = c8 + j;
        float v = 0.f;
        if (col < 12)      v = x[(size_t)r * 12 + col];
        else if (col < 44) v = emb[(size_t)r * 32 + (col - 12)];
        h[j] = bf16_of(v);
    }
    *(int4*)(Xh + (size_t)r * 64 + c8) = *(int4*)h;
}

__global__ __launch_bounds__(256) void cat3_pack(  // [x(12) | preds_id(6)] -> [M][32] hi only
    const float* __restrict__ x, const float* __restrict__ dout,
    unsigned short* __restrict__ Xh)
{
    const int gid = blockIdx.x * 256 + threadIdx.x;   // M*4 threads
    const int r = gid >> 2, c8 = (gid & 3) * 8;
    unsigned short h[8];
    #pragma unroll
    for (int j = 0; j < 8; ++j) {
        const int col = c8 + j;
        float v = 0.f;
        if (col < 12)      v = x[(size_t)r * 12 + col];
        else if (col < 18) v = dout[(size_t)r * 12 + (col - 12)];
        h[j] = bf16_of(v);
    }
    *(int4*)(Xh + (size_t)r * 32 + c8) = *(int4*)h;
}

// ======================= MFMA GEMM: 2-phase pipelined, BK=32, double-buffered LDS ==============
// TWO=false: bf16x3 fp32-accurate (Ah*Bh + Ah*Bl + Al*Bh). TWO=true: bf16 activations,
// hi/lo weights (2 MFMA). MF=1 (BM=32) for narrow-grid layers: grid 4x larger -> 4 blocks/CU
// 16 waves/CU (was 1-2 blocks/CU, the latency-bound hole). MF=2 for Np=256 TWO layers.
template<int MF, int NF, bool TWO>
__global__ __launch_bounds__(256, (MF == 2 && !TWO) ? 3 : 4) void gemm_mfma3(
    const unsigned short* __restrict__ Ah, const unsigned short* __restrict__ Al,
    const unsigned short* __restrict__ Bh, const unsigned short* __restrict__ Bl,
    const float* __restrict__ bias, int Kp, int N, int act,
    float* __restrict__ Cf, int ldcf,
    unsigned short* __restrict__ Ch, unsigned short* __restrict__ Cl, int ldcb, int padN)
{
    constexpr int BM  = MF * 32;
    constexpr int PA  = BM * 32;          // shorts per A half per phase
    constexpr int PB  = NF * 32 * 32;     // shorts per B half per phase
    constexpr int NAH = TWO ? 1 : 2;      // A halves staged
    constexpr int PH  = NAH * PA + 2 * PB;
    __shared__ unsigned short lds[2 * PH];

    const int tid  = threadIdx.x;
    const int wave = tid >> 6, lane = tid & 63;
    const int wr = wave >> 1, wc = wave & 1;
    const int row0 = blockIdx.x * BM;
    const int col0 = blockIdx.y * (NF * 32);
    const int r16 = lane & 15, kg = lane >> 4;

    f32x4 acc[MF][NF];
    #pragma unroll
    for (int m = 0; m < MF; ++m)
        #pragma unroll
        for (int n = 0; n < NF; ++n)
            #pragma unroll
            for (int r = 0; r < 4; ++r) acc[m][n][r] = 0.f;

    auto STAGE = [&](int p, int k0) {
        unsigned short* base = lds + p * PH;
        #pragma unroll
        for (int c = tid; c < BM * 4; c += 256) {
            const int r  = c >> 2;
            const int kc = ((c & 3) ^ (r & 3)) * 8;          // inverse-swizzled source chunk
            const size_t go = (size_t)(row0 + r) * Kp + k0 + kc;
            gload16(Ah + go, base + c * 8);
            if (!TWO) gload16(Al + go, base + PA + c * 8);
        }
        #pragma unroll
        for (int c = tid; c < NF * 128; c += 256) {
            const int r  = c >> 2;
            const int kc = ((c & 3) ^ (r & 3)) * 8;
            const size_t go = (size_t)(col0 + r) * Kp + k0 + kc;
            gload16(Bh + go, base + NAH * PA + c * 8);
            gload16(Bl + go, base + NAH * PA + PB + c * 8);
        }
    };

    auto COMPUTE = [&](int p) {
        unsigned short* base = lds + p * PH;
        short8 ah[MF], al[MF], bh[NF], bl[NF];
        #pragma unroll
        for (int m = 0; m < MF; ++m) {
            const int rr = wr * (MF * 16) + m * 16 + r16;
            const int off = rr * 32 + ((kg ^ (rr & 3)) * 8);  // swizzled read
            ah[m] = *(const short8*)&base[off];
            if (!TWO) al[m] = *(const short8*)&base[PA + off];
        }
        #pragma unroll
        for (int n = 0; n < NF; ++n) {
            const int br = (NF == 4 ? wc * 64 + n * 16 : wc * 16) + r16;
            const int off = br * 32 + ((kg ^ (br & 3)) * 8);
            bh[n] = *(const short8*)&base[NAH * PA + off];
            bl[n] = *(const short8*)&base[NAH * PA + PB + off];
        }
        #pragma unroll
        for (int m = 0; m < MF; ++m)
            #pragma unroll
            for (int n = 0; n < NF; ++n) {
                acc[m][n] = __builtin_amdgcn_mfma_f32_16x16x32_bf16(ah[m], bh[n], acc[m][n], 0, 0, 0);
                acc[m][n] = __builtin_amdgcn_mfma_f32_16x16x32_bf16(ah[m], bl[n], acc[m][n], 0, 0, 0);
                if (!TWO)
                    acc[m][n] = __builtin_amdgcn_mfma_f32_16x16x32_bf16(al[m], bh[n], acc[m][n], 0, 0, 0);
            }
    };

    const int nt = Kp >> 5;
    STAGE(0, 0);
    __syncthreads();                 // drain prologue loads
    int cur = 0;
    for (int t = 0; t < nt; ++t) {
        if (t + 1 < nt) STAGE(cur ^ 1, (t + 1) * 32);   // issue next tile BEFORE compute
        COMPUTE(cur);
        __syncthreads();             // vmcnt(0)+barrier: next tile landed, cur free to reuse
        cur ^= 1;
    }

    // epilogue: C/D layout col=lane&15, row=(lane>>4)*4+reg
    #pragma unroll
    for (int m = 0; m < MF; ++m) {
        #pragma unroll
        for (int n = 0; n < NF; ++n) {
            const int col = col0 + (NF == 4 ? wc * 64 + n * 16 : wc * 16) + r16;
            #pragma unroll
            for (int r = 0; r < 4; ++r) {
                const int row = row0 + wr * (MF * 16) + m * 16 + kg * 4 + r;
                if (col < N) {
                    float v = acc[m][n][r] + bias[col];
                    if (act) v = elu_fast(v);
                    if (Cf) {
                        Cf[(size_t)row * ldcf + col] = v;
                    } else if (TWO) {
                        Ch[(size_t)row * ldcb + col] = bf16_of(v);
                    } else {
                        unsigned short h, l;
                        split_bf16(v, h, l);
                        Ch[(size_t)row * ldcb + col] = h;
                        Cl[(size_t)row * ldcb + col] = l;
                    }
                } else if (Ch && col < padN) {
                    Ch[(size_t)row * ldcb + col] = 0;
                    if (!TWO) Cl[(size_t)row * ldcb + col] = 0;
                }
            }
        }
    }
}

// ======================= GravNet: projections s,h and |s|^2 (conv 0 only) =======================
__global__ __launch_bounds__(64) void conv_proj(
    const float* __restrict__ emb, const float* __restrict__ Ws,
    const float* __restrict__ bs, const float* __restrict__ Wh,
    const float* __restrict__ bh,
    float* __restrict__ s_out, float* __restrict__ sq_out, float* __restrict__ h_out)
{
    __shared__ float ws_s[32 * 4];
    __shared__ float wh_s[32 * 8];
    __shared__ float bs_s[4];
    __shared__ float bh_s[8];
    const int tid = threadIdx.x;
    for (int i = tid; i < 128; i += 64) ws_s[i] = Ws[i];
    for (int i = tid; i < 256; i += 64) wh_s[i] = Wh[i];
    if (tid < 4) bs_s[tid] = bs[tid];
    if (tid >= 8 && tid < 16) bh_s[tid - 8] = bh[tid - 8];
    __syncthreads();

    const int row = blockIdx.x * 64 + tid;
    float e[32];
    #pragma unroll
    for (int i = 0; i < 8; i++)
        *(float4*)&e[i * 4] = *(const float4*)(emb + (size_t)row * 32 + i * 4);

    float sv[4];
    #pragma unroll
    for (int c = 0; c < 4; c++) {
        float a = e[0] * ws_s[c];
        #pragma unroll
        for (int k = 1; k < 32; k++) a = fmaf(e[k], ws_s[k * 4 + c], a);
        sv[c] = a + bs_s[c];
    }
    float sq = sv[0] * sv[0];
    sq = fmaf(sv[1], sv[1], sq);
    sq = fmaf(sv[2], sv[2], sq);
    sq = fmaf(sv[3], sv[3], sq);

    float hv[8];
    #pragma unroll
    for (int c = 0; c < 8; c++) {
        float a = e[0] * wh_s[c];
        #pragma unroll
        for (int k = 1; k < 32; k++) a = fmaf(e[k], wh_s[k * 8 + c], a);
        hv[c] = a + bh_s[c];
    }

    *(float4*)(s_out + (size_t)row * 4) = *(float4*)&sv[0];
    sq_out[row] = sq;
    *(float4*)(h_out + (size_t)row * 8)     = *(float4*)&hv[0];
    *(float4*)(h_out + (size_t)row * 8 + 4) = *(float4*)&hv[4];
}

// ======================= kNN top-4 (r9 config: RP=1, 16 splits, 256 cands, csq staged) =========
__device__ __forceinline__ void merge44(const float* ad, const int* ai,
                                        const float* bd, const int* bi,
                                        float* od, int* oi)
{
    int a = 0, b = 0;
    #pragma unroll
    for (int k = 0; k < 4; ++k) {
        bool ta;
        if (a < 4 && b < 4)
            ta = (ad[a] < bd[b]) || (ad[a] == bd[b] && ai[a] < bi[b]);
        else
            ta = (a < 4);
        if (ta) { od[k] = ad[a]; oi[k] = ai[a]; ++a; }
        else    { od[k] = bd[b]; oi[k] = bi[b]; ++b; }
    }
}

__global__ __launch_bounds__(256) void knn_top4_part(
    const float* __restrict__ s, const float* __restrict__ sq,
    float* __restrict__ pd, int* __restrict__ pi)
{
    __shared__ float4 cs[256];
    __shared__ float  csq[256];

    const int tid  = threadIdx.x;
    const int pg   = blockIdx.x >> 4;          // point group (256 points)
    const int sp   = blockIdx.x & 15;          // candidate split (256 cands)
    const int p0   = pg << 8;
    const int base = (p0 >> 12) << 12;         // batch base row
    const int row  = p0 + tid;                 // this thread's point

    const float4 sn  = *(const float4*)(s + (size_t)row * 4);
    const float  sqn = sq[row];

    const int m0 = sp << 8;
    {
        const int gm = base + m0 + tid;
        cs[tid]  = *(const float4*)(s + (size_t)gm * 4);
        csq[tid] = sq[gm];
    }
    __syncthreads();

    float bd[4] = {FLT_MAX, FLT_MAX, FLT_MAX, FLT_MAX};
    int   bi[4] = {INT_MAX, INT_MAX, INT_MAX, INT_MAX};

    #pragma unroll 8
    for (int i = 0; i < 256; ++i) {
        const float4 cm = cs[i];
        const float  cq = csq[i];
        float dot = sn.x * cm.x;
        dot = fmaf(sn.y, cm.y, dot);
        dot = fmaf(sn.z, cm.z, dot);
        dot = fmaf(sn.w, cm.w, dot);
        const float d2 = (sqn + cq) - 2.f * dot;
        const int m = m0 + i;                  // ascending per thread
        const bool c3 = d2 < bd[3];
        const bool c2 = d2 < bd[2];
        const bool c1 = d2 < bd[1];
        const bool c0 = d2 < bd[0];
        bi[3] = c3 ? (c2 ? bi[2] : m) : bi[3];
        bi[2] = c2 ? (c1 ? bi[1] : m) : bi[2];
        bi[1] = c1 ? (c0 ? bi[0] : m) : bi[1];
        bi[0] = c0 ? m : bi[0];
        bd[3] = __builtin_amdgcn_fmed3f(bd[2], bd[3], d2);
        bd[2] = __builtin_amdgcn_fmed3f(bd[1], bd[2], d2);
        bd[1] = __builtin_amdgcn_fmed3f(bd[0], bd[1], d2);
        bd[0] = fminf(bd[0], d2);
    }

    // partial layout: [pg][sp][256 points][4]
    const size_t o = (((size_t)pg * 16 + sp) * 256 + tid) * 4;
    *(float4*)(pd + o) = *(float4*)&bd[0];
    *(int4*)(pi + o)   = *(int4*)&bi[0];
}

// ======================= GravNet: merge + aggregate + out-linear (+ fused next-conv proj) ======
__global__ __launch_bounds__(64) void conv_agg(
    const float* __restrict__ emb, const float* __restrict__ h,
    const float* __restrict__ pd, const int* __restrict__ pi,
    const float* __restrict__ Wo1, const float* __restrict__ Wo2,
    const float* __restrict__ bo2, float* __restrict__ out,
    const float* __restrict__ Ws2, const float* __restrict__ bs2,
    const float* __restrict__ Wh2, const float* __restrict__ bh2,
    float* __restrict__ s_out, float* __restrict__ sq_out, float* __restrict__ h_out)
{
    __shared__ float w1[1024];
    __shared__ float w2[512];
    __shared__ float b2[32];
    __shared__ float ws_s[128];
    __shared__ float wh_s[256];
    __shared__ float bs_s[4];
    __shared__ float bh_s[8];
    const int tid = threadIdx.x;
    for (int i = tid; i < 1024; i += 64) w1[i] = Wo1[i];
    for (int i = tid; i < 512;  i += 64) w2[i] = Wo2[i];
    if (tid < 32) b2[tid] = bo2[tid];
    if (Ws2) {
        for (int i = tid; i < 128; i += 64) ws_s[i] = Ws2[i];
        for (int i = tid; i < 256; i += 64) wh_s[i] = Wh2[i];
        if (tid < 4) bs_s[tid] = bs2[tid];
        if (tid >= 8 && tid < 16) bh_s[tid - 8] = bh2[tid - 8];
    }
    __syncthreads();

    const int row  = blockIdx.x * 64 + tid;
    const int pg   = row >> 8;
    const int ln   = row & 255;
    const int base = (row >> 12) << 12;

    // ---- fold-merge the 16 candidate-split partials (lexicographic (d2, idx))
    float ad[4];
    int   ai[4];
    {
        const size_t o = ((size_t)pg * 16 * 256 + ln) * 4;
        *(float4*)&ad[0] = *(const float4*)(pd + o);
        *(int4*)&ai[0]   = *(const int4*)(pi + o);
    }
    #pragma unroll
    for (int sp = 1; sp < 16; ++sp) {
        const size_t o = (((size_t)pg * 16 + sp) * 256 + ln) * 4;
        float bdv[4], od[4];
        int   biv[4], oi[4];
        *(float4*)&bdv[0] = *(const float4*)(pd + o);
        *(int4*)&biv[0]   = *(const int4*)(pi + o);
        merge44(ad, ai, bdv, biv, od, oi);
        #pragma unroll
        for (int k = 0; k < 4; ++k) { ad[k] = od[k]; ai[k] = oi[k]; }
    }

    // ---- gather + weighted mean/max aggregate
    float e[32];
    #pragma unroll
    for (int i = 0; i < 8; i++)
        *(float4*)&e[i * 4] = *(const float4*)(emb + (size_t)row * 32 + i * 4);

    float msum[8], mmax[8];
    #pragma unroll
    for (int dd = 0; dd < 8; dd++) { msum[dd] = 0.f; mmax[dd] = -FLT_MAX; }

    #pragma unroll
    for (int k = 0; k < 4; k++) {
        const int g    = base + ai[k];
        const float wk = __expf(-10.f * fmaxf(ad[k], 0.f));
        float hv[8];
        *(float4*)&hv[0] = *(const float4*)(h + (size_t)g * 8);
        *(float4*)&hv[4] = *(const float4*)(h + (size_t)g * 8 + 4);
        #pragma unroll
        for (int dd = 0; dd < 8; dd++) {
            const float m = hv[dd] * wk;
            msum[dd] += m;
            mmax[dd] = fmaxf(mmax[dd], m);
        }
    }

    float agg[16];
    #pragma unroll
    for (int dd = 0; dd < 8; dd++) { agg[dd] = msum[dd] * 0.25f; agg[8 + dd] = mmax[dd]; }

    float o32[32];
    #pragma unroll
    for (int j = 0; j < 32; j++) {
        float a = e[0] * w1[j];
        #pragma unroll
        for (int k = 1; k < 32; k++) a = fmaf(e[k], w1[k * 32 + j], a);
        float g = agg[0] * w2[j];
        #pragma unroll
        for (int k = 1; k < 16; k++) g = fmaf(agg[k], w2[k * 32 + j], g);
        o32[j] = a + g + b2[j];
        out[(size_t)row * 32 + j] = o32[j];
    }

    // ---- fused next-conv projection (bit-identical to conv_proj on same values)
    if (Ws2) {
        float sv[4];
        #pragma unroll
        for (int c = 0; c < 4; c++) {
            float a = o32[0] * ws_s[c];
            #pragma unroll
            for (int k = 1; k < 32; k++) a = fmaf(o32[k], ws_s[k * 4 + c], a);
            sv[c] = a + bs_s[c];
        }
        float sq2 = sv[0] * sv[0];
        sq2 = fmaf(sv[1], sv[1], sq2);
        sq2 = fmaf(sv[2], sv[2], sq2);
        sq2 = fmaf(sv[3], sv[3], sq2);

        float hv[8];
        #pragma unroll
        for (int c = 0; c < 8; c++) {
            float a = o32[0] * wh_s[c];
            #pragma unroll
            for (int k = 1; k < 32; k++) a = fmaf(o32[k], wh_s[k * 8 + c], a);
            hv[c] = a + bh_s[c];
        }
        *(float4*)(s_out + (size_t)row * 4) = *(float4*)&sv[0];
        sq_out[row] = sq2;
        *(float4*)(h_out + (size_t)row * 8)     = *(float4*)&hv[0];
        *(float4*)(h_out + (size_t)row * 8 + 4) = *(float4*)&hv[4];
    }
}

// ======================= host launcher =======================
extern "C" void kernel_launch(void* const* d_in, const int* in_sizes, int n_in,
                              void* d_out, int out_size, void* d_ws, size_t ws_size,
                              hipStream_t stream)
{
    const float* x = (const float*)d_in[0];
    const float* nn1_w[4] = {(const float*)d_in[1], (const float*)d_in[3], (const float*)d_in[5], (const float*)d_in[7]};
    const float* nn1_b[4] = {(const float*)d_in[2], (const float*)d_in[4], (const float*)d_in[6], (const float*)d_in[8]};
    const float* nn2_w[4] = {(const float*)d_in[9],  (const float*)d_in[11], (const float*)d_in[13], (const float*)d_in[15]};
    const float* nn2_b[4] = {(const float*)d_in[10], (const float*)d_in[12], (const float*)d_in[14], (const float*)d_in[16]};
    const float* nn3_w[4] = {(const float*)d_in[17], (const float*)d_in[19], (const float*)d_in[21], (const float*)d_in[23]};
    const float* nn3_b[4] = {(const float*)d_in[18], (const float*)d_in[20], (const float*)d_in[22], (const float*)d_in[24]};
    const float* conv_ws  = (const float*)d_in[25];  // [3,32,4]
    const float* conv_bs  = (const float*)d_in[26];  // [3,4]
    const float* conv_wh  = (const float*)d_in[27];  // [3,32,8]
    const float* conv_bh  = (const float*)d_in[28];  // [3,8]
    const float* conv_wo1 = (const float*)d_in[29];  // [3,32,32]
    const float* conv_wo2 = (const float*)d_in[30];  // [3,16,32]
    const float* conv_bo2 = (const float*)d_in[31];  // [3,32]

    float* outp = (float*)d_out;
    const int M = NN_TOTAL;

    // ---- workspace partition
    char* p = (char*)d_ws;
    auto take = [&](size_t bytes) { char* r = p; p += (bytes + 255) & ~size_t(255); return r; };
    unsigned short* Xa_h = (unsigned short*)take((size_t)M * 256 * 2);
    unsigned short* Xa_l = (unsigned short*)take((size_t)M * 256 * 2);
    unsigned short* Xb_h = (unsigned short*)take((size_t)M * 256 * 2);
    unsigned short* Xb_l = (unsigned short*)take((size_t)M * 256 * 2);
    float* embA = (float*)take((size_t)M * 32 * 4);
    float* embB = (float*)take((size_t)M * 32 * 4);
    unsigned short* WH = (unsigned short*)take((size_t)450000 * 2);
    unsigned short* WL = (unsigned short*)take((size_t)450000 * 2);

    // conv scratch aliased over Xa..Xb (all four dead during conv loop)
    char* q = (char*)Xa_h;
    auto takeq = [&](size_t bytes) { char* r = q; q += (bytes + 255) & ~size_t(255); return r; };
    float* sbuf  = (float*)takeq((size_t)M * 4 * 4);
    float* sqb   = (float*)takeq((size_t)M * 4);
    float* hbufA = (float*)takeq((size_t)M * 8 * 4);
    float* hbufB = (float*)takeq((size_t)M * 8 * 4);
    float* pdb   = (float*)takeq((size_t)M * 16 * 4 * 4);
    int*   pib   = (int*)takeq((size_t)M * 16 * 4 * 4);

    // ---- fused weight prep (Kp multiple of 32 for BK=32; Np=32 for narrow layers)
    struct LW { int K, N, Kp, Np, off; };
    LW lw[12];
    const float* Ws_[12] = {nn1_w[0], nn1_w[1], nn1_w[2], nn1_w[3],
                            nn2_w[0], nn2_w[1], nn2_w[2], nn2_w[3],
                            nn3_w[0], nn3_w[1], nn3_w[2], nn3_w[3]};
    const int Ks_[12] = {12, 126, 126, 126,  44, 256, 256, 256,  18, 256, 256, 256};
    const int Ns_[12] = {126, 126, 126, 32,  256, 256, 256, 6,   256, 256, 256, 6};
    PrepArgs pa;
    int off = 0, blk = 0;
    for (int i = 0; i < 12; ++i) {
        lw[i].K = Ks_[i]; lw[i].N = Ns_[i];
        lw[i].Kp = (Ks_[i] + 31) & ~31;
        lw[i].Np = (Ns_[i] <= 32) ? 32 : ((Ns_[i] + 127) & ~127);
        lw[i].off = off;
        pa.W[i] = Ws_[i];
        pa.K[i] = Ks_[i]; pa.N[i] = Ns_[i];
        pa.ksh[i] = __builtin_ctz(lw[i].Kp);
        pa.off[i] = off;
        pa.blk0[i] = blk;
        off += lw[i].Kp * lw[i].Np;
        blk += lw[i].Kp * lw[i].Np / 256;
    }
    prep_all<<<blk, 256, 0, stream>>>(pa, WH, WL);

    auto mfma = [&](const unsigned short* Ah, const unsigned short* Al, int li,
                    const float* bias, int act,
                    float* Cf, int ldcf,
                    unsigned short* Chh, unsigned short* Cll, int ldcb, int padN,
                    int mf, int nf, bool two) {
        const int gy = (nf == 4) ? lw[li].Np / 128 : 1;
        if (mf == 2 && nf == 4 && two) {
            dim3 g(M / 64, gy);
            gemm_mfma3<2, 4, true><<<g, 256, 0, stream>>>(Ah, Al, WH + lw[li].off, WL + lw[li].off,
                bias, lw[li].Kp, lw[li].N, act, Cf, ldcf, Chh, Cll, ldcb, padN);
        } else if (mf == 1 && nf == 4 && !two) {
            dim3 g(M / 32, gy);
            gemm_mfma3<1, 4, false><<<g, 256, 0, stream>>>(Ah, Al, WH + lw[li].off, WL + lw[li].off,
                bias, lw[li].Kp, lw[li].N, act, Cf, ldcf, Chh, Cll, ldcb, padN);
        } else if (mf == 1 && nf == 1 && !two) {
            dim3 g(M / 32, 1);
            gemm_mfma3<1, 1, false><<<g, 256, 0, stream>>>(Ah, Al, WH + lw[li].off, WL + lw[li].off,
                bias, lw[li].Kp, lw[li].N, act, Cf, ldcf, Chh, Cll, ldcb, padN);
        } else { // mf==1, nf==1, two
            dim3 g(M / 32, 1);
            gemm_mfma3<1, 1, true><<<g, 256, 0, stream>>>(Ah, Al, WH + lw[li].off, WL + lw[li].off,
                bias, lw[li].Kp, lw[li].N, act, Cf, ldcf, Chh, Cll, ldcb, padN);
        }
    };

    // ---- nn1 (fp32-accurate bf16x3; feeds kNN selections): 12 -> 126^3 -> 32(emb fp32)
    pack_x32<<<M * 4 / 256, 256, 0, stream>>>(x, Xa_h, Xa_l);
    mfma(Xa_h, Xa_l, 0, nn1_b[0], 1, nullptr, 0, Xb_h, Xb_l, 128, 128, 1, 4, false);
    mfma(Xb_h, Xb_l, 1, nn1_b[1], 1, nullptr, 0, Xa_h, Xa_l, 128, 128, 1, 4, false);
    mfma(Xa_h, Xa_l, 2, nn1_b[2], 1, nullptr, 0, Xb_h, Xb_l, 128, 128, 1, 4, false);
    mfma(Xb_h, Xb_l, 3, nn1_b[3], 0, embA, 32, nullptr, nullptr, 0, 0, 1, 1, false);

    // ---- 3 GravNet convs (fp32; proj of conv1,2 fused into agg of conv0,1)
    conv_proj<<<M / 64, 64, 0, stream>>>(
        embA, conv_ws, conv_bs, conv_wh, conv_bh, sbuf, sqb, hbufA);
    float* ecur = embA;  float* enext = embB;
    float* hcur = hbufA; float* hnext = hbufB;
    for (int i = 0; i < 3; i++) {
        knn_top4_part<<<(M / 256) * 16, 256, 0, stream>>>(sbuf, sqb, pdb, pib);
        const bool fuse = (i < 2);
        conv_agg<<<M / 64, 64, 0, stream>>>(
            ecur, hcur, pdb, pib,
            conv_wo1 + i * 1024, conv_wo2 + i * 512, conv_bo2 + i * 32, enext,
            fuse ? conv_ws + (i + 1) * 128 : nullptr,
            fuse ? conv_bs + (i + 1) * 4   : nullptr,
            fuse ? conv_wh + (i + 1) * 256 : nullptr,
            fuse ? conv_bh + (i + 1) * 8   : nullptr,
            sbuf, sqb, hnext);
        float* t = ecur; ecur = enext; enext = t;
        t = hcur; hcur = hnext; hnext = t;
    }
    // ecur == final emb

    // ---- nn2 (TWO: bf16 activations, hi/lo weights; smooth path)
    cat2_pack<<<M * 8 / 256, 256, 0, stream>>>(x, ecur, Xa_h);
    mfma(Xa_h, nullptr, 4, nn2_b[0], 1, nullptr, 0, Xb_h, nullptr, 256, 256, 2, 4, true);
    mfma(Xb_h, nullptr, 5, nn2_b[1], 1, nullptr, 0, Xa_h, nullptr, 256, 256, 2, 4, true);
    mfma(Xa_h, nullptr, 6, nn2_b[2], 1, nullptr, 0, Xb_h, nullptr, 256, 256, 2, 4, true);
    mfma(Xb_h, nullptr, 7, nn2_b[3], 0, outp, 12, nullptr, nullptr, 0, 0, 1, 1, true);

    // ---- nn3 (TWO): cat(x,preds_id)=18 -> 256^3 -> 6 (d_out cols 6..11)
    cat3_pack<<<M * 4 / 256, 256, 0, stream>>>(x, outp, Xa_h);
    mfma(Xa_h, nullptr, 8, nn3_b[0], 1, nullptr, 0, Xb_h, nullptr, 256, 256, 2, 4, true);
    mfma(Xb_h, nullptr, 9, nn3_b[1], 1, nullptr, 0, Xa_h, nullptr, 256, 256, 2, 4, true);
    mfma(Xa_h, nullptr, 10, nn3_b[2], 1, nullptr, 0, Xb_h, nullptr, 256, 256, 2, 4, true);
    mfma(Xb_h, nullptr, 11, nn3_b[3], 0, outp + 6, 12, nullptr, nullptr, 0, 0, 1, 1, true);
}